// Round 4
// baseline (553.366 us; speedup 1.0000x reference)
//
#include <hip/hip_runtime.h>
#include <math.h>

#define N_B 16
#define T_LEN 4096

typedef float f32x4  __attribute__((ext_vector_type(4)));
typedef float f32x16 __attribute__((ext_vector_type(16)));
typedef _Float16 half8 __attribute__((ext_vector_type(8)));

struct LL { long a, b; };   // 16B container for two ds_read_b64

// ---- workspace layout (float offsets) ----
static const size_t OFF_A    = 0;            // 16*128*4096
static const size_t OFF_B    = 8388608;      // 16*256*4096
static const size_t OFF_Z    = 25165824;     // 16*64*4096
static const size_t OFF_WS   = 29360128;     // split-weight region
static const size_t OFF_CBS  = 29540352;     // codebook split (32768 floats)
static const size_t OFF_C2   = 29683712;
static const size_t OFF_ST   = 29684736;
static const size_t OFF_LOSS = 29685760;

// split-weight offsets (floats from OFF_WS); decoder reuses after enc convs
static const size_t WS_E1 = 0;        // 6*3*128*16 = 36864 floats
static const size_t WS_E2 = 36864;    // 8*3*256*16 = 98304 floats
static const size_t WS_E3 = 135168;   // 16*1*64*16 = 16384 floats -> 151552
static const size_t WS_D1 = 0;        // 4*3*256*16 = 49152 floats
static const size_t WS_D2 = 49152;    // 16*3*128*16= 98304 floats
static const size_t WS_D3 = 147456;   // 8*3*80*16  = 30720 floats -> 178176

// scaled f16 split: v = hi + lo * 2^-12, error ~2^-24 relative (f32-grade).
__device__ inline void f2h2(float v, short& hi, short& lo) {
    _Float16 h = (_Float16)v;
    float r = (v - (float)h) * 4096.0f;
    _Float16 l = (_Float16)r;
    hi = __builtin_bit_cast(short, h);
    lo = __builtin_bit_cast(short, l);
}
__device__ inline float h2f(short s) {
    return (float)__builtin_bit_cast(_Float16, s);
}

// split-weight fragments for 32x32x16: dst [(c2*KS+k)*2+p][co][16 ci-shorts]
// (c2 = 16-ci block, NC2 = 2*ceil(C_IN/32), zero-padded)
template<int C_IN, int C_OUT, int KS>
__device__ inline void wsplit_fill(const float* __restrict__ w,
                                   short* __restrict__ dst, int e) {
    int i  = e & 15;
    int r  = e >> 4;
    int co = r % C_OUT;
    int r2 = r / C_OUT;          // c2*KS + k
    int k  = r2 % KS;
    int c2 = r2 / KS;
    int ci = c2 * 16 + i;
    float v = (ci < C_IN) ? w[((size_t)co * C_IN + ci) * KS + k] : 0.f;
    short h, l; f2h2(v, h, l);
    size_t base = ((size_t)(c2 * KS + k) * 2 * C_OUT + co) * 16 + i;
    dst[base] = h;
    dst[base + (size_t)C_OUT * 16] = l;
}

__global__ __launch_bounds__(256) void prep_k(
        const float* __restrict__ w1, const float* __restrict__ w2,
        const float* __restrict__ w3, const float* __restrict__ cb,
        float* wsf) {
    int e = blockIdx.x * 256 + threadIdx.x;
    if (e < 36864)        wsplit_fill<80, 128, 3>(w1, (short*)(wsf + OFF_WS + WS_E1), e);
    else if (e < 135168)  wsplit_fill<128, 256, 3>(w2, (short*)(wsf + OFF_WS + WS_E2), e - 36864);
    else if (e < 151552)  wsplit_fill<256, 64, 1>(w3, (short*)(wsf + OFF_WS + WS_E3), e - 135168);
    else if (e < 152064) {
        int c = e - 151552;
        const float* p = cb + (size_t)c * 64;
        double s = 0.0;
        for (int d = 0; d < 64; ++d) { double v = p[d]; s += v * v; }
        wsf[OFF_C2 + c] = (float)s;
    } else if (e < 184832) {
        // codebook split fragments (16x16x32 path in vq_k): [ks][plane][code][32]
        int e2   = e - 152064;
        int i    = e2 & 31;
        int r    = e2 >> 5;
        int code = r & 511;
        int ks   = r >> 9;
        float v  = cb[(size_t)code * 64 + ks * 32 + i];
        short h, l; f2h2(v, h, l);
        short* dst = (short*)(wsf + OFF_CBS);
        dst[((size_t)(ks * 2 + 0) * 512 + code) * 32 + i] = h;
        dst[((size_t)(ks * 2 + 1) * 512 + code) * 32 + i] = l;
    } else if (e == 184832) {
        *(double*)(wsf + OFF_LOSS) = 0.0;
    }
}

__global__ __launch_bounds__(256) void prep2_k(
        const float* __restrict__ wd1, const float* __restrict__ wd2,
        const float* __restrict__ wd3, float* wsf) {
    int e = blockIdx.x * 256 + threadIdx.x;
    if (e < 49152)        wsplit_fill<64, 256, 3>(wd1, (short*)(wsf + OFF_WS + WS_D1), e);
    else if (e < 147456)  wsplit_fill<256, 128, 3>(wd2, (short*)(wsf + OFF_WS + WS_D2), e - 49152);
    else if (e < 178176)  wsplit_fill<128, 80, 3>(wd3, (short*)(wsf + OFF_WS + WS_D3), e - 147456);
}

// ---- conv1d via scaled-f16 split MFMA 32x32x16, 2x2 wave grid ----
// GEMM M=co, N=t, K=ci per tap. Block 64co x TT t; wave = 32co x TT/2 t.
// Assumed maps (probe-verified): A[m=lane&31][k=(lane>>5)*8+j],
// B[k=(lane>>5)*8+j][n=lane&31], D[m=(reg&3)+8*(reg>>2)+4*(lane>>5)][n=lane&31].
// Split planes xh/xl, row stride 36 shorts (18 dwords -> 2-way-free b16 writes).
// Optional fused BN-stat partials: per (block,wc,co) double2 into part[].
template<int C_IN, int C_OUT, int KS, bool BN_IN, bool STATS>
__global__ __launch_bounds__(256, 2) void fconv_k(
        const float* __restrict__ x, const short* __restrict__ wsp,
        const float* __restrict__ bias, const float2* __restrict__ stats,
        float* __restrict__ out, double2* __restrict__ part) {
    constexpr int NCH   = (C_IN + 31) / 32;
    constexpr int HALO  = KS / 2;
    constexpr int TT    = (KS == 1) ? 64 : 128;
    constexpr int HT    = TT / 2;
    constexpr int NTT   = HT / 32;
    constexpr int NTILE = T_LEN / TT;
    constexpr int XR    = TT + KS - 1;
    constexpr int RS2   = 36;
    constexpr int TQ    = TT / 4;

    __shared__ __align__(16) short xh[XR * RS2];
    __shared__ __align__(16) short xl[XR * RS2];
    __shared__ int okf;

    const int tid  = threadIdx.x;
    const int lane = tid & 63;
    const int wv   = tid >> 6;
    const int wr   = wv >> 1;      // co strip (32)
    const int wc   = wv & 1;       // t half
    const int nn   = lane & 31;
    const int hsel = lane >> 5;

    const int n    = blockIdx.x / NTILE;
    const int t0   = (blockIdx.x % NTILE) * TT;
    const int co0  = blockIdx.y * 64;
    const int co_l = co0 + wr * 32 + nn;

    // ---- integer probe for 32x32x16 f16 layout ----
    bool ok = true;
    {
        half8 pa, pb;
#pragma unroll
        for (int j = 0; j < 8; ++j) {
            int k = hsel * 8 + j;
            pa[j] = (_Float16)(float)(nn + 2 * k);
            pb[j] = (_Float16)(float)(nn + 3 * k);
        }
        f32x16 pd;
#pragma unroll
        for (int r = 0; r < 16; ++r) pd[r] = 0.f;
        pd = __builtin_amdgcn_mfma_f32_32x32x16_f16(pa, pb, pd, 0, 0, 0);
#pragma unroll
        for (int r = 0; r < 16; ++r) {
            int m = (r & 3) + 8 * (r >> 2) + 4 * hsel;
            float e = (float)(16 * m * nn + 360 * m + 240 * nn + 7440);
            if (pd[r] != e) ok = false;
        }
    }
    if (tid == 0) okf = 1;
    __syncthreads();
    if (!ok) okf = 0;
    __syncthreads();
    const bool okp = (okf != 0);

    f32x16 a0[NTT], a1[NTT];
#pragma unroll
    for (int tt = 0; tt < NTT; ++tt)
#pragma unroll
        for (int r = 0; r < 16; ++r) { a0[tt][r] = 0.f; a1[tt][r] = 0.f; }

#pragma unroll 1
    for (int c = 0; c < NCH; ++c) {
        __syncthreads();
        // ---- stage x tile into split planes (2-way-free b16 writes) ----
        for (int e = tid; e < 32 * TQ; e += 256) {
            const int ci  = e / TQ;
            const int tq  = e % TQ;
            const int cig = c * 32 + ci;
            float v[4] = {0.f, 0.f, 0.f, 0.f};
            if (cig < C_IN) {
                const float* xp = x + ((size_t)(n * C_IN + cig)) * T_LEN + t0 + tq;
#pragma unroll
                for (int j = 0; j < 4; ++j) v[j] = xp[TQ * j];
                if (BN_IN) {
                    float2 sst = stats[cig];
#pragma unroll
                    for (int j = 0; j < 4; ++j) v[j] = fmaxf(fmaf(v[j], sst.x, sst.y), 0.f);
                }
            }
#pragma unroll
            for (int j = 0; j < 4; ++j) {
                short h, l; f2h2(v[j], h, l);
                const int row = HALO + tq + TQ * j;
                xh[row * RS2 + ci] = h;
                xl[row * RS2 + ci] = l;
            }
        }
        if (KS == 3) {
            if (tid < 64) {
                const int ci   = tid & 31;
                const int side = tid >> 5;
                const int cig  = c * 32 + ci;
                const int gt   = side ? (t0 + TT) : (t0 - 1);
                float vv = 0.f;
                if (cig < C_IN && gt >= 0 && gt < T_LEN) {
                    vv = x[((size_t)(n * C_IN + cig)) * T_LEN + gt];
                    if (BN_IN) {
                        float2 sst = stats[cig];
                        vv = fmaxf(fmaf(vv, sst.x, sst.y), 0.f);
                    }
                }
                short h, l; f2h2(vv, h, l);
                const int row = side ? (XR - 1) : 0;
                xh[row * RS2 + ci] = h;
                xl[row * RS2 + ci] = l;
            }
        }
        __syncthreads();

        if (okp) {
#pragma unroll
            for (int s = 0; s < 2; ++s) {
                const int c2 = c * 2 + s;
                half8 ah[KS], al[KS];
                half8 z8 = {0, 0, 0, 0, 0, 0, 0, 0};
#pragma unroll
                for (int k = 0; k < KS; ++k) {
                    const short* wp = wsp
                        + ((size_t)(c2 * KS + k) * 2 * C_OUT + co_l) * 16 + hsel * 8;
                    ah[k] = (co_l < C_OUT) ? *(const half8*)wp : z8;
                    al[k] = (co_l < C_OUT) ? *(const half8*)(wp + (size_t)C_OUT * 16) : z8;
                }
#pragma unroll
                for (int k = 0; k < KS; ++k) {
#pragma unroll
                    for (int tt = 0; tt < NTT; ++tt) {
                        const int row = wc * HT + tt * 32 + nn + k;
                        const int col = s * 16 + hsel * 8;
                        const short* ph = &xh[row * RS2 + col];
                        const short* pl = &xl[row * RS2 + col];
                        LL th, tl;
                        th.a = *(const long*)ph; th.b = *(const long*)(ph + 4);
                        tl.a = *(const long*)pl; tl.b = *(const long*)(pl + 4);
                        half8 bh = __builtin_bit_cast(half8, th);
                        half8 bl = __builtin_bit_cast(half8, tl);
                        a0[tt] = __builtin_amdgcn_mfma_f32_32x32x16_f16(ah[k], bh, a0[tt], 0, 0, 0);
                        a1[tt] = __builtin_amdgcn_mfma_f32_32x32x16_f16(ah[k], bl, a1[tt], 0, 0, 0);
                        a1[tt] = __builtin_amdgcn_mfma_f32_32x32x16_f16(al[k], bh, a1[tt], 0, 0, 0);
                    }
                }
            }
        } else {
            // correctness fallback from the same tiles, same D-map
#pragma unroll 1
            for (int s = 0; s < 2; ++s) {
                const int c2 = c * 2 + s;
#pragma unroll 1
                for (int k = 0; k < KS; ++k) {
#pragma unroll 1
                    for (int i = 0; i < 16; ++i) {
                        float wvv[16];
#pragma unroll
                        for (int r = 0; r < 16; ++r) {
                            const int m  = (r & 3) + 8 * (r >> 2) + 4 * hsel;
                            const int co = co0 + wr * 32 + m;
                            float vv = 0.f;
                            if (co < C_OUT) {
                                const size_t bb =
                                    ((size_t)(c2 * KS + k) * 2 * C_OUT + co) * 16 + i;
                                vv = h2f(wsp[bb])
                                   + h2f(wsp[bb + (size_t)C_OUT * 16]) * 0.000244140625f;
                            }
                            wvv[r] = vv;
                        }
#pragma unroll
                        for (int tt = 0; tt < NTT; ++tt) {
                            const int row = wc * HT + tt * 32 + nn + k;
                            const int col = s * 16 + i;
                            const float xv = h2f(xh[row * RS2 + col])
                                           + h2f(xl[row * RS2 + col]) * 0.000244140625f;
#pragma unroll
                            for (int r = 0; r < 16; ++r)
                                a0[tt][r] = fmaf(wvv[r], xv, a0[tt][r]);
                        }
                    }
                }
            }
        }
    }

    // ---- epilogue: store + optional fused BN-stat partials ----
    const int plinear = (blockIdx.y * gridDim.x + blockIdx.x) * 2 + wc;
#pragma unroll
    for (int r = 0; r < 16; ++r) {
        const int m  = (r & 3) + 8 * (r >> 2) + 4 * hsel;
        const int co = co0 + wr * 32 + m;
        const float bv = (co < C_OUT) ? bias[co] : 0.f;
        double s1 = 0.0, s2 = 0.0;
#pragma unroll
        for (int tt = 0; tt < NTT; ++tt) {
            const float v = fmaf(a1[tt][r], 0.000244140625f, a0[tt][r]) + bv;
            if (co < C_OUT)
                out[((size_t)(n * C_OUT + co)) * T_LEN + t0 + wc * HT + tt * 32 + nn] = v;
            if (STATS) { s1 += (double)v; s2 += (double)v * (double)v; }
        }
        if (STATS) {
#pragma unroll
            for (int off = 1; off <= 16; off <<= 1) {
                s1 += __shfl_xor(s1, off);
                s2 += __shfl_xor(s2, off);
            }
            if (nn == 0)
                part[(size_t)plinear * 64 + wr * 32 + m] = make_double2(s1, s2);
        }
    }
}

// ---- BN stats: reduce 1024 per-(block,wc) partials per channel, finalize ----
__global__ __launch_bounds__(256) void stats_k(
        const double2* __restrict__ part, const float* __restrict__ g,
        const float* __restrict__ b, float2* __restrict__ stats) {
    const int c = blockIdx.x;
    const int tid = threadIdx.x;
    double s1 = 0.0, s2 = 0.0;
    for (int j = tid; j < 1024; j += 256) {
        double2 v = part[((size_t)(c >> 6) * 1024 + j) * 64 + (c & 63)];
        s1 += v.x; s2 += v.y;
    }
    __shared__ double r1[256], r2[256];
    r1[tid] = s1; r2[tid] = s2;
    __syncthreads();
    for (int s = 128; s > 0; s >>= 1) {
        if (tid < s) { r1[tid] += r1[tid + s]; r2[tid] += r2[tid + s]; }
        __syncthreads();
    }
    if (tid == 0) {
        double m   = r1[0] / 65536.0;
        double var = r2[0] / 65536.0 - m * m;
        double sc  = (double)g[c] / sqrt(var + 1e-5);
        stats[c] = make_float2((float)sc, (float)((double)b[c] - m * sc));
    }
}

// ---- VQ via scaled-f16 split MFMA (16x16x32, unchanged from r3) ----
__global__ __launch_bounds__(256) void vq_k(
        const float* __restrict__ z, const float* __restrict__ cb,
        const short* __restrict__ cbs, const float* __restrict__ c2,
        float* __restrict__ q, float* __restrict__ idx_out,
        double* __restrict__ loss) {
    __shared__ __align__(16) float zs[64 * 68];
    __shared__ __align__(16) short zh[64 * 136];
    __shared__ float  c2s[512];
    __shared__ float  szf_s[64];
    __shared__ int    idxs[64];
    __shared__ double dred[256];

    const int tid  = threadIdx.x;
    const int lane = tid & 63;
    const int wv   = tid >> 6;
    const int ln   = lane & 15;
    const int q4   = lane >> 4;
    const int n    = blockIdx.x >> 6;
    const int t0   = (blockIdx.x & 63) * 64;

    for (int e = tid; e < 512; e += 256) c2s[e] = c2[e];
    for (int e = tid; e < 1024; e += 256) {
        const int d  = e >> 4;
        const int tq = e & 15;
        const float* zp = z + ((size_t)(n * 64 + d)) * T_LEN + t0 + tq;
        const int ks = d >> 5, i = d & 31;
#pragma unroll
        for (int j = 0; j < 4; ++j) {
            const int t = tq + 16 * j;
            float v = zp[16 * j];
            zs[t * 68 + d] = v;
            short h, l; f2h2(v, h, l);
            zh[t * 136 + (ks * 2 + 0) * 32 + i] = h;
            zh[t * 136 + (ks * 2 + 1) * 32 + i] = l;
        }
    }
    __syncthreads();
    if (tid < 64) {
        double s = 0.0;
        const float* zr = &zs[tid * 68];
        for (int d = 0; d < 64; ++d) { double v = zr[d]; s += v * v; }
        szf_s[tid] = (float)s;
    }
    __syncthreads();

    const short* zr = &zh[(wv * 16 + ln) * 136 + q4 * 8];
    const half8 bh0 = *(const half8*)&zr[0];
    const half8 bl0 = *(const half8*)&zr[32];
    const half8 bh1 = *(const half8*)&zr[64];
    const half8 bl1 = *(const half8*)&zr[96];
    const float As  = szf_s[wv * 16 + ln];

    float bs = 3.0e38f;
    int   bi = 1 << 30;

#pragma unroll 4
    for (int ct = 0; ct < 32; ++ct) {
        const short* ap = cbs + ((size_t)(ct * 16 + ln)) * 32 + q4 * 8;
        const half8 ah0 = *(const half8*)&ap[0];
        const half8 al0 = *(const half8*)&ap[512 * 32];
        const half8 ah1 = *(const half8*)&ap[2 * 512 * 32];
        const half8 al1 = *(const half8*)&ap[3 * 512 * 32];
        f32x4 a0 = {0.f, 0.f, 0.f, 0.f};
        f32x4 a1 = {0.f, 0.f, 0.f, 0.f};
        a0 = __builtin_amdgcn_mfma_f32_16x16x32_f16(ah0, bh0, a0, 0, 0, 0);
        a1 = __builtin_amdgcn_mfma_f32_16x16x32_f16(ah0, bl0, a1, 0, 0, 0);
        a1 = __builtin_amdgcn_mfma_f32_16x16x32_f16(al0, bh0, a1, 0, 0, 0);
        a0 = __builtin_amdgcn_mfma_f32_16x16x32_f16(ah1, bh1, a0, 0, 0, 0);
        a1 = __builtin_amdgcn_mfma_f32_16x16x32_f16(ah1, bl1, a1, 0, 0, 0);
        a1 = __builtin_amdgcn_mfma_f32_16x16x32_f16(al1, bh1, a1, 0, 0, 0);
#pragma unroll
        for (int r = 0; r < 4; ++r) {
            const int code = ct * 16 + q4 * 4 + r;
            const float m32 = fmaf(a1[r], 0.000244140625f, a0[r]);
            const float A   = As + c2s[code];
            const float s   = A - 2.0f * m32;
            if (s < bs || (s == bs && code < bi)) { bs = s; bi = code; }
        }
    }
#pragma unroll
    for (int off = 16; off <= 32; off <<= 1) {
        const float os = __shfl_xor(bs, off);
        const int   oi = __shfl_xor(bi, off);
        if (os < bs || (os == bs && oi < bi)) { bs = os; bi = oi; }
    }
    if (q4 == 0) {
        const int t = wv * 16 + ln;
        idxs[t] = bi;
        idx_out[(size_t)n * T_LEN + t0 + t] = (float)bi;
    }
    __syncthreads();

    {
        const int g = tid >> 6, t = tid & 63;
        const int bi2 = idxs[t];
        double ls = 0.0;
        for (int dd = 0; dd < 16; ++dd) {
            const int d = g * 16 + dd;
            const float qv = cb[(size_t)bi2 * 64 + d];
            const float zv = zs[t * 68 + d];
            const double df = (double)qv - (double)zv;
            ls += df * df;
            q[((size_t)(n * 64 + d)) * T_LEN + t0 + t] = qv;
        }
        dred[tid] = ls;
    }
    __syncthreads();
    for (int s = 128; s > 0; s >>= 1) {
        if (tid < s) dred[tid] += dred[tid + s];
        __syncthreads();
    }
    if (tid == 0) atomicAdd(loss, dred[0]);
}

__global__ void fin_k(const double* __restrict__ loss, float* __restrict__ out) {
    if (threadIdx.x == 0 && blockIdx.x == 0)
        out[0] = (float)(1.25 * (*loss) / 4194304.0);
}

extern "C" void kernel_launch(void* const* d_in, const int* in_sizes, int n_in,
                              void* d_out, int out_size, void* d_ws, size_t ws_size,
                              hipStream_t stream) {
    const float* x      = (const float*)d_in[0];
    const float* enc_w1 = (const float*)d_in[1];
    const float* enc_b1 = (const float*)d_in[2];
    const float* bn1_g  = (const float*)d_in[3];
    const float* bn1_b  = (const float*)d_in[4];
    const float* enc_w2 = (const float*)d_in[5];
    const float* enc_b2 = (const float*)d_in[6];
    const float* bn2_g  = (const float*)d_in[7];
    const float* bn2_b  = (const float*)d_in[8];
    const float* enc_w3 = (const float*)d_in[9];
    const float* enc_b3 = (const float*)d_in[10];
    const float* cb     = (const float*)d_in[11];
    const float* dec_w1 = (const float*)d_in[12];
    const float* dec_b1 = (const float*)d_in[13];
    const float* dbn1_g = (const float*)d_in[14];
    const float* dbn1_b = (const float*)d_in[15];
    const float* dec_w2 = (const float*)d_in[16];
    const float* dec_b2 = (const float*)d_in[17];
    const float* dbn2_g = (const float*)d_in[18];
    const float* dbn2_b = (const float*)d_in[19];
    const float* dec_w3 = (const float*)d_in[20];
    const float* dec_b3 = (const float*)d_in[21];

    float* wsf   = (float*)d_ws;
    float* outf  = (float*)d_out;
    float* A     = wsf + OFF_A;
    float* Bb    = wsf + OFF_B;
    float* Z     = wsf + OFF_Z;
    float2* st   = (float2*)(wsf + OFF_ST);
    double* lossp = (double*)(wsf + OFF_LOSS);

    const short* wsE1 = (const short*)(wsf + OFF_WS + WS_E1);
    const short* wsE2 = (const short*)(wsf + OFF_WS + WS_E2);
    const short* wsE3 = (const short*)(wsf + OFF_WS + WS_E3);
    const short* wsD1 = (const short*)(wsf + OFF_WS + WS_D1);
    const short* wsD2 = (const short*)(wsf + OFF_WS + WS_D2);
    const short* wsD3 = (const short*)(wsf + OFF_WS + WS_D3);
    const short* cbs  = (const short*)(wsf + OFF_CBS);

    // partial-stat buffers live in whichever big buffer is dead at that stage
    double2* pE1 = (double2*)Bb;   // enc1: Bb free until enc2 writes it
    double2* pE2 = (double2*)Z;    // enc2: Z free until enc3 writes it
    double2* pD1 = (double2*)A;    // dec1: A free until dec2 writes it
    double2* pD2 = (double2*)Z;    // dec2: Z dead after dec1 consumed it

    prep_k<<<723, 256, 0, stream>>>(enc_w1, enc_w2, enc_w3, cb, wsf);

    // encoder
    fconv_k<80, 128, 3, false, true><<<dim3(512, 2), 256, 0, stream>>>(
        x, wsE1, enc_b1, nullptr, A, pE1);
    stats_k<<<128, 256, 0, stream>>>(pE1, bn1_g, bn1_b, st);
    fconv_k<128, 256, 3, true, true><<<dim3(512, 4), 256, 0, stream>>>(
        A, wsE2, enc_b2, st, Bb, pE2);
    stats_k<<<256, 256, 0, stream>>>(pE2, bn2_g, bn2_b, st);
    fconv_k<256, 64, 1, true, false><<<dim3(1024, 1), 256, 0, stream>>>(
        Bb, wsE3, enc_b3, st, Z, nullptr);

    // decoder splits overwrite (now-dead) encoder splits
    prep2_k<<<696, 256, 0, stream>>>(dec_w1, dec_w2, dec_w3, wsf);

    // vector quantizer
    vq_k<<<1024, 256, 0, stream>>>(Z, cb, cbs, wsf + OFF_C2, Z,
                                   outf + 5242881, lossp);
    fin_k<<<1, 64, 0, stream>>>(lossp, outf + 5242880);

    // decoder
    fconv_k<64, 256, 3, false, true><<<dim3(512, 4), 256, 0, stream>>>(
        Z, wsD1, dec_b1, nullptr, Bb, pD1);
    stats_k<<<256, 256, 0, stream>>>(pD1, dbn1_g, dbn1_b, st);
    fconv_k<256, 128, 3, true, true><<<dim3(512, 2), 256, 0, stream>>>(
        Bb, wsD2, dec_b2, st, A, pD2);
    stats_k<<<128, 256, 0, stream>>>(pD2, dbn2_g, dbn2_b, st);
    fconv_k<128, 80, 3, true, false><<<dim3(512, 2), 256, 0, stream>>>(
        A, wsD3, dec_b3, st, outf, nullptr);
}

// Round 5
// 507.295 us; speedup vs baseline: 1.0908x; 1.0908x over previous
//
#include <hip/hip_runtime.h>
#include <math.h>

#define N_B 16
#define T_LEN 4096

typedef float f32x4  __attribute__((ext_vector_type(4)));
typedef _Float16 half8 __attribute__((ext_vector_type(8)));

struct LL { long a, b; };   // two ds_read_b64 (rows are 8B- not 16B-aligned)

// ---- workspace layout (float offsets) ----
static const size_t OFF_A    = 0;            // 16*128*4096
static const size_t OFF_B    = 8388608;      // 16*256*4096
static const size_t OFF_Z    = 25165824;     // 16*64*4096
static const size_t OFF_WS   = 29360128;     // split-weight region
static const size_t OFF_CBS  = 29540352;     // codebook split (32768 floats)
static const size_t OFF_C2   = 29683712;
static const size_t OFF_ST   = 29684736;
static const size_t OFF_LOSS = 29685760;

// split-weight offsets (floats from OFF_WS); decoder reuses after enc convs
static const size_t WS_E1 = 0;        // 3*3*128*32 = 36864 floats
static const size_t WS_E2 = 36864;    // 4*3*256*32 = 98304 floats
static const size_t WS_E3 = 135168;   // 8*1*64*32  = 16384 floats -> 151552
static const size_t WS_D1 = 0;        // 2*3*256*32 = 49152 floats
static const size_t WS_D2 = 49152;    // 8*3*128*32 = 98304 floats
static const size_t WS_D3 = 147456;   // 4*3*80*32  = 30720 floats -> 178176

// scaled f16 split: v = hi + lo * 2^-12, error ~2^-24 relative (f32-grade).
__device__ inline void f2h2(float v, short& hi, short& lo) {
    _Float16 h = (_Float16)v;
    float r = (v - (float)h) * 4096.0f;
    _Float16 l = (_Float16)r;
    hi = __builtin_bit_cast(short, h);
    lo = __builtin_bit_cast(short, l);
}
__device__ inline float h2f(short s) {
    return (float)__builtin_bit_cast(_Float16, s);
}

// fill split-weight fragments: dst layout [(c*KS+k)*2+p][co][32 ci-shorts]
template<int C_IN, int C_OUT, int KS>
__device__ inline void wsplit_fill(const float* __restrict__ w,
                                   short* __restrict__ dst, int e) {
    int i  = e & 31;
    int r  = e >> 5;
    int co = r % C_OUT;
    int r2 = r / C_OUT;          // c*KS + k
    int k  = r2 % KS;
    int c  = r2 / KS;
    int ci = c * 32 + i;
    float v = (ci < C_IN) ? w[((size_t)co * C_IN + ci) * KS + k] : 0.f;
    short h, l; f2h2(v, h, l);
    size_t base = ((size_t)(c * KS + k) * 2 * C_OUT + co) * 32 + i;
    dst[base] = h;
    dst[base + (size_t)C_OUT * 32] = l;
}

__global__ __launch_bounds__(256) void prep_k(
        const float* __restrict__ w1, const float* __restrict__ w2,
        const float* __restrict__ w3, const float* __restrict__ cb,
        float* wsf) {
    int e = blockIdx.x * 256 + threadIdx.x;
    if (e < 36864)        wsplit_fill<80, 128, 3>(w1, (short*)(wsf + OFF_WS + WS_E1), e);
    else if (e < 135168)  wsplit_fill<128, 256, 3>(w2, (short*)(wsf + OFF_WS + WS_E2), e - 36864);
    else if (e < 151552)  wsplit_fill<256, 64, 1>(w3, (short*)(wsf + OFF_WS + WS_E3), e - 135168);
    else if (e < 152064) {
        int c = e - 151552;
        const float* p = cb + (size_t)c * 64;
        double s = 0.0;
        for (int d = 0; d < 64; ++d) { double v = p[d]; s += v * v; }
        wsf[OFF_C2 + c] = (float)s;
    } else if (e < 184832) {
        // codebook split fragments (vq_k): [ks][plane][code][32 d-shorts]
        int e2   = e - 152064;
        int i    = e2 & 31;
        int r    = e2 >> 5;
        int code = r & 511;
        int ks   = r >> 9;
        float v  = cb[(size_t)code * 64 + ks * 32 + i];
        short h, l; f2h2(v, h, l);
        short* dst = (short*)(wsf + OFF_CBS);
        dst[((size_t)(ks * 2 + 0) * 512 + code) * 32 + i] = h;
        dst[((size_t)(ks * 2 + 1) * 512 + code) * 32 + i] = l;
    } else if (e == 184832) {
        *(double*)(wsf + OFF_LOSS) = 0.0;
    }
}

__global__ __launch_bounds__(256) void prep2_k(
        const float* __restrict__ wd1, const float* __restrict__ wd2,
        const float* __restrict__ wd3, float* wsf) {
    int e = blockIdx.x * 256 + threadIdx.x;
    if (e < 49152)        wsplit_fill<64, 256, 3>(wd1, (short*)(wsf + OFF_WS + WS_D1), e);
    else if (e < 147456)  wsplit_fill<256, 128, 3>(wd2, (short*)(wsf + OFF_WS + WS_D2), e - 49152);
    else if (e < 178176)  wsplit_fill<128, 80, 3>(wd3, (short*)(wsf + OFF_WS + WS_D3), e - 147456);
}

// ---- conv1d via scaled-f16 split MFMA 16x16x32, 2(co)x2(t) wave grid ----
// GEMM M=co, N=t, K=ci per tap. Block 64co x TT t; wave = 32co x TT/2 t.
// Wave's B fragments read once per (tap,tt), reused for 2 co-subtiles
// (halves r3's LDS read traffic). Maps (HW-verified r1-r3):
// A[m=lane&15][k=q*8+j], B[k=q*8+j][n=lane&15], D[m=q*4+r][n=lane&15].
// LDS: separate hi/lo planes, row stride 36 shorts (18 dwords -> 2-way-free
// b16 staging writes, balanced b64-pair fragment reads; r4-proven 2e6 confl).
// Optional fused BN-stat partials per (block, wc, co) -> part[].
template<int C_IN, int C_OUT, int KS, bool BN_IN, bool STATS>
__global__ __launch_bounds__(256, 2) void fconv_k(
        const float* __restrict__ x, const short* __restrict__ wsp,
        const float* __restrict__ bias, const float2* __restrict__ stats,
        float* __restrict__ out, double2* __restrict__ part) {
    constexpr int NCH   = (C_IN + 31) / 32;
    constexpr int HALO  = KS / 2;
    constexpr int TT    = (KS == 1) ? 64 : 128;
    constexpr int HT    = TT / 2;
    constexpr int NTT   = HT / 16;               // 4 (KS=3) or 2 (KS=1)
    constexpr int NTILE = T_LEN / TT;
    constexpr int XR    = TT + KS - 1;
    constexpr int RS    = 36;                    // shorts/row (72B, 18 dwords)
    constexpr int TQ    = TT / 4;

    __shared__ __align__(16) short xh[XR * RS];
    __shared__ __align__(16) short xl[XR * RS];
    __shared__ int okf;

    const int tid  = threadIdx.x;
    const int lane = tid & 63;
    const int wv   = tid >> 6;
    const int wr   = wv >> 1;      // co strip (32)
    const int wc   = wv & 1;       // t half
    const int ln   = lane & 15;
    const int q    = lane >> 4;

    const int n    = blockIdx.x / NTILE;
    const int t0   = (blockIdx.x % NTILE) * TT;
    const int co0  = blockIdx.y * 64;

    // ---- integer probe for 16x16x32 f16 layout (HW-verified r1-r3) ----
    bool ok = true;
    {
        half8 pa, pb;
#pragma unroll
        for (int j = 0; j < 8; ++j) {
            int kk = q * 8 + j;
            pa[j] = (_Float16)(float)(ln + 2 * kk);
            pb[j] = (_Float16)(float)(ln + 3 * kk);
        }
        f32x4 pd = {0.f, 0.f, 0.f, 0.f};
        pd = __builtin_amdgcn_mfma_f32_16x16x32_f16(pa, pb, pd, 0, 0, 0);
#pragma unroll
        for (int r = 0; r < 4; ++r) {
            int m = q * 4 + r;
            float e = (float)(32 * m * ln + 1488 * m + 992 * ln + 62496);
            if (pd[r] != e) ok = false;
        }
    }
    if (tid == 0) okf = 1;
    __syncthreads();
    if (!ok) okf = 0;
    __syncthreads();
    const bool okp = (okf != 0);

    f32x4 a0[2][NTT], a1[2][NTT];
#pragma unroll
    for (int cs = 0; cs < 2; ++cs)
#pragma unroll
        for (int tt = 0; tt < NTT; ++tt)
#pragma unroll
            for (int i = 0; i < 4; ++i) { a0[cs][tt][i] = 0.f; a1[cs][tt][i] = 0.f; }

#pragma unroll 1
    for (int c = 0; c < NCH; ++c) {
        __syncthreads();
        // ---- stage x tile into split planes ----
        for (int e = tid; e < 32 * TQ; e += 256) {
            const int ci  = e / TQ;
            const int tq  = e % TQ;
            const int cig = c * 32 + ci;
            float v[4] = {0.f, 0.f, 0.f, 0.f};
            if (cig < C_IN) {
                const float* xp = x + ((size_t)(n * C_IN + cig)) * T_LEN + t0 + tq;
#pragma unroll
                for (int j = 0; j < 4; ++j) v[j] = xp[TQ * j];
                if (BN_IN) {
                    float2 sst = stats[cig];
#pragma unroll
                    for (int j = 0; j < 4; ++j) v[j] = fmaxf(fmaf(v[j], sst.x, sst.y), 0.f);
                }
            }
#pragma unroll
            for (int j = 0; j < 4; ++j) {
                short h, l; f2h2(v[j], h, l);
                const int row = HALO + tq + TQ * j;
                xh[row * RS + ci] = h;
                xl[row * RS + ci] = l;
            }
        }
        if (KS == 3) {
            if (tid < 64) {
                const int ci   = tid & 31;
                const int side = tid >> 5;
                const int cig  = c * 32 + ci;
                const int gt   = side ? (t0 + TT) : (t0 - 1);
                float vv = 0.f;
                if (cig < C_IN && gt >= 0 && gt < T_LEN) {
                    vv = x[((size_t)(n * C_IN + cig)) * T_LEN + gt];
                    if (BN_IN) {
                        float2 sst = stats[cig];
                        vv = fmaxf(fmaf(vv, sst.x, sst.y), 0.f);
                    }
                }
                short h, l; f2h2(vv, h, l);
                const int row = side ? (XR - 1) : 0;
                xh[row * RS + ci] = h;
                xl[row * RS + ci] = l;
            }
        }
        __syncthreads();

        if (okp) {
#pragma unroll
            for (int k = 0; k < KS; ++k) {
                // A fragments for this tap: 2 co-subtiles x 2 planes (L2-hot)
                half8 ah[2], al[2];
                half8 z8 = {0, 0, 0, 0, 0, 0, 0, 0};
#pragma unroll
                for (int cs = 0; cs < 2; ++cs) {
                    const int co_l = co0 + wr * 32 + cs * 16 + ln;
                    const short* wp = wsp
                        + ((size_t)(c * KS + k) * 2 * C_OUT + co_l) * 32 + q * 8;
                    ah[cs] = (co_l < C_OUT) ? *(const half8*)wp : z8;
                    al[cs] = (co_l < C_OUT) ? *(const half8*)(wp + (size_t)C_OUT * 32) : z8;
                }
#pragma unroll
                for (int tt = 0; tt < NTT; ++tt) {
                    const int row = wc * HT + tt * 16 + ln + k;
                    const short* ph = &xh[row * RS + q * 8];
                    const short* pl = &xl[row * RS + q * 8];
                    LL th, tl;
                    th.a = *(const long*)ph; th.b = *(const long*)(ph + 4);
                    tl.a = *(const long*)pl; tl.b = *(const long*)(pl + 4);
                    half8 bh = __builtin_bit_cast(half8, th);
                    half8 bl = __builtin_bit_cast(half8, tl);
#pragma unroll
                    for (int cs = 0; cs < 2; ++cs) {
                        a0[cs][tt] = __builtin_amdgcn_mfma_f32_16x16x32_f16(ah[cs], bh, a0[cs][tt], 0, 0, 0);
                        a1[cs][tt] = __builtin_amdgcn_mfma_f32_16x16x32_f16(ah[cs], bl, a1[cs][tt], 0, 0, 0);
                        a1[cs][tt] = __builtin_amdgcn_mfma_f32_16x16x32_f16(al[cs], bh, a1[cs][tt], 0, 0, 0);
                    }
                }
            }
        } else {
            // correctness fallback from the same tiles, same D-map
#pragma unroll 1
            for (int k = 0; k < KS; ++k)
#pragma unroll 1
                for (int ci = 0; ci < 32; ++ci) {
                    float wv_[2][4];
#pragma unroll
                    for (int cs = 0; cs < 2; ++cs)
#pragma unroll
                        for (int r = 0; r < 4; ++r) {
                            const int co = co0 + wr * 32 + cs * 16 + q * 4 + r;
                            float vv = 0.f;
                            if (co < C_OUT) {
                                const size_t bb =
                                    ((size_t)(c * KS + k) * 2 * C_OUT + co) * 32 + ci;
                                vv = h2f(wsp[bb])
                                   + h2f(wsp[bb + (size_t)C_OUT * 32]) * 0.000244140625f;
                            }
                            wv_[cs][r] = vv;
                        }
#pragma unroll
                    for (int tt = 0; tt < NTT; ++tt) {
                        const int row = wc * HT + tt * 16 + ln + k;
                        const float xv = h2f(xh[row * RS + ci])
                                       + h2f(xl[row * RS + ci]) * 0.000244140625f;
#pragma unroll
                        for (int cs = 0; cs < 2; ++cs)
#pragma unroll
                            for (int r = 0; r < 4; ++r)
                                a0[cs][tt][r] = fmaf(wv_[cs][r], xv, a0[cs][tt][r]);
                    }
                }
        }
    }

    // ---- epilogue: store + optional fused BN-stat partials ----
    const int plinear = (blockIdx.y * gridDim.x + blockIdx.x) * 2 + wc;
#pragma unroll
    for (int cs = 0; cs < 2; ++cs) {
#pragma unroll
        for (int r = 0; r < 4; ++r) {
            const int co = co0 + wr * 32 + cs * 16 + q * 4 + r;
            const float bv = (co < C_OUT) ? bias[co] : 0.f;
            double s1 = 0.0, s2 = 0.0;
#pragma unroll
            for (int tt = 0; tt < NTT; ++tt) {
                const float v = fmaf(a1[cs][tt][r], 0.000244140625f, a0[cs][tt][r]) + bv;
                if (co < C_OUT)
                    out[((size_t)(n * C_OUT + co)) * T_LEN + t0 + wc * HT + tt * 16 + ln] = v;
                if (STATS) { s1 += (double)v; s2 += (double)v * (double)v; }
            }
            if (STATS) {
#pragma unroll
                for (int off = 1; off <= 8; off <<= 1) {
                    s1 += __shfl_xor(s1, off);
                    s2 += __shfl_xor(s2, off);
                }
                if (ln == 0)
                    part[(size_t)plinear * 64 + wr * 32 + cs * 16 + q * 4 + r] =
                        make_double2(s1, s2);
            }
        }
    }
}

// ---- BN stats: reduce 1024 per-(block,wc) partials per channel, finalize ----
__global__ __launch_bounds__(256) void stats_k(
        const double2* __restrict__ part, const float* __restrict__ g,
        const float* __restrict__ b, float2* __restrict__ stats) {
    const int c = blockIdx.x;
    const int tid = threadIdx.x;
    double s1 = 0.0, s2 = 0.0;
    for (int j = tid; j < 1024; j += 256) {
        double2 v = part[((size_t)(c >> 6) * 1024 + j) * 64 + (c & 63)];
        s1 += v.x; s2 += v.y;
    }
    __shared__ double r1[256], r2[256];
    r1[tid] = s1; r2[tid] = s2;
    __syncthreads();
    for (int s = 128; s > 0; s >>= 1) {
        if (tid < s) { r1[tid] += r1[tid + s]; r2[tid] += r2[tid + s]; }
        __syncthreads();
    }
    if (tid == 0) {
        double m   = r1[0] / 65536.0;
        double var = r2[0] / 65536.0 - m * m;
        double sc  = (double)g[c] / sqrt(var + 1e-5);
        stats[c] = make_float2((float)sc, (float)((double)b[c] - m * sc));
    }
}

// ---- VQ via scaled-f16 split MFMA (16x16x32, r3-proven) ----
__global__ __launch_bounds__(256) void vq_k(
        const float* __restrict__ z, const float* __restrict__ cb,
        const short* __restrict__ cbs, const float* __restrict__ c2,
        float* __restrict__ q, float* __restrict__ idx_out,
        double* __restrict__ loss) {
    __shared__ __align__(16) float zs[64 * 68];
    __shared__ __align__(16) short zh[64 * 136];
    __shared__ float  c2s[512];
    __shared__ float  szf_s[64];
    __shared__ int    idxs[64];
    __shared__ double dred[256];

    const int tid  = threadIdx.x;
    const int lane = tid & 63;
    const int wv   = tid >> 6;
    const int ln   = lane & 15;
    const int q4   = lane >> 4;
    const int n    = blockIdx.x >> 6;
    const int t0   = (blockIdx.x & 63) * 64;

    for (int e = tid; e < 512; e += 256) c2s[e] = c2[e];
    for (int e = tid; e < 1024; e += 256) {
        const int d  = e >> 4;
        const int tq = e & 15;
        const float* zp = z + ((size_t)(n * 64 + d)) * T_LEN + t0 + tq;
        const int ks = d >> 5, i = d & 31;
#pragma unroll
        for (int j = 0; j < 4; ++j) {
            const int t = tq + 16 * j;
            float v = zp[16 * j];
            zs[t * 68 + d] = v;
            short h, l; f2h2(v, h, l);
            zh[t * 136 + (ks * 2 + 0) * 32 + i] = h;
            zh[t * 136 + (ks * 2 + 1) * 32 + i] = l;
        }
    }
    __syncthreads();
    if (tid < 64) {
        double s = 0.0;
        const float* zr = &zs[tid * 68];
        for (int d = 0; d < 64; ++d) { double v = zr[d]; s += v * v; }
        szf_s[tid] = (float)s;
    }
    __syncthreads();

    const short* zr = &zh[(wv * 16 + ln) * 136 + q4 * 8];
    const half8 bh0 = *(const half8*)&zr[0];
    const half8 bl0 = *(const half8*)&zr[32];
    const half8 bh1 = *(const half8*)&zr[64];
    const half8 bl1 = *(const half8*)&zr[96];
    const float As  = szf_s[wv * 16 + ln];

    float bs = 3.0e38f;
    int   bi = 1 << 30;

#pragma unroll 4
    for (int ct = 0; ct < 32; ++ct) {
        const short* ap = cbs + ((size_t)(ct * 16 + ln)) * 32 + q4 * 8;
        const half8 ah0 = *(const half8*)&ap[0];
        const half8 al0 = *(const half8*)&ap[512 * 32];
        const half8 ah1 = *(const half8*)&ap[2 * 512 * 32];
        const half8 al1 = *(const half8*)&ap[3 * 512 * 32];
        f32x4 a0 = {0.f, 0.f, 0.f, 0.f};
        f32x4 a1 = {0.f, 0.f, 0.f, 0.f};
        a0 = __builtin_amdgcn_mfma_f32_16x16x32_f16(ah0, bh0, a0, 0, 0, 0);
        a1 = __builtin_amdgcn_mfma_f32_16x16x32_f16(ah0, bl0, a1, 0, 0, 0);
        a1 = __builtin_amdgcn_mfma_f32_16x16x32_f16(al0, bh0, a1, 0, 0, 0);
        a0 = __builtin_amdgcn_mfma_f32_16x16x32_f16(ah1, bh1, a0, 0, 0, 0);
        a1 = __builtin_amdgcn_mfma_f32_16x16x32_f16(ah1, bl1, a1, 0, 0, 0);
        a1 = __builtin_amdgcn_mfma_f32_16x16x32_f16(al1, bh1, a1, 0, 0, 0);
#pragma unroll
        for (int r = 0; r < 4; ++r) {
            const int code = ct * 16 + q4 * 4 + r;
            const float m32 = fmaf(a1[r], 0.000244140625f, a0[r]);
            const float A   = As + c2s[code];
            const float s   = A - 2.0f * m32;
            if (s < bs || (s == bs && code < bi)) { bs = s; bi = code; }
        }
    }
#pragma unroll
    for (int off = 16; off <= 32; off <<= 1) {
        const float os = __shfl_xor(bs, off);
        const int   oi = __shfl_xor(bi, off);
        if (os < bs || (os == bs && oi < bi)) { bs = os; bi = oi; }
    }
    if (q4 == 0) {
        const int t = wv * 16 + ln;
        idxs[t] = bi;
        idx_out[(size_t)n * T_LEN + t0 + t] = (float)bi;
    }
    __syncthreads();

    {
        const int g = tid >> 6, t = tid & 63;
        const int bi2 = idxs[t];
        double ls = 0.0;
        for (int dd = 0; dd < 16; ++dd) {
            const int d = g * 16 + dd;
            const float qv = cb[(size_t)bi2 * 64 + d];
            const float zv = zs[t * 68 + d];
            const double df = (double)qv - (double)zv;
            ls += df * df;
            q[((size_t)(n * 64 + d)) * T_LEN + t0 + t] = qv;
        }
        dred[tid] = ls;
    }
    __syncthreads();
    for (int s = 128; s > 0; s >>= 1) {
        if (tid < s) dred[tid] += dred[tid + s];
        __syncthreads();
    }
    if (tid == 0) atomicAdd(loss, dred[0]);
}

__global__ void fin_k(const double* __restrict__ loss, float* __restrict__ out) {
    if (threadIdx.x == 0 && blockIdx.x == 0)
        out[0] = (float)(1.25 * (*loss) / 4194304.0);
}

extern "C" void kernel_launch(void* const* d_in, const int* in_sizes, int n_in,
                              void* d_out, int out_size, void* d_ws, size_t ws_size,
                              hipStream_t stream) {
    const float* x      = (const float*)d_in[0];
    const float* enc_w1 = (const float*)d_in[1];
    const float* enc_b1 = (const float*)d_in[2];
    const float* bn1_g  = (const float*)d_in[3];
    const float* bn1_b  = (const float*)d_in[4];
    const float* enc_w2 = (const float*)d_in[5];
    const float* enc_b2 = (const float*)d_in[6];
    const float* bn2_g  = (const float*)d_in[7];
    const float* bn2_b  = (const float*)d_in[8];
    const float* enc_w3 = (const float*)d_in[9];
    const float* enc_b3 = (const float*)d_in[10];
    const float* cb     = (const float*)d_in[11];
    const float* dec_w1 = (const float*)d_in[12];
    const float* dec_b1 = (const float*)d_in[13];
    const float* dbn1_g = (const float*)d_in[14];
    const float* dbn1_b = (const float*)d_in[15];
    const float* dec_w2 = (const float*)d_in[16];
    const float* dec_b2 = (const float*)d_in[17];
    const float* dbn2_g = (const float*)d_in[18];
    const float* dbn2_b = (const float*)d_in[19];
    const float* dec_w3 = (const float*)d_in[20];
    const float* dec_b3 = (const float*)d_in[21];

    float* wsf   = (float*)d_ws;
    float* outf  = (float*)d_out;
    float* A     = wsf + OFF_A;
    float* Bb    = wsf + OFF_B;
    float* Z     = wsf + OFF_Z;
    float2* st   = (float2*)(wsf + OFF_ST);
    double* lossp = (double*)(wsf + OFF_LOSS);

    const short* wsE1 = (const short*)(wsf + OFF_WS + WS_E1);
    const short* wsE2 = (const short*)(wsf + OFF_WS + WS_E2);
    const short* wsE3 = (const short*)(wsf + OFF_WS + WS_E3);
    const short* wsD1 = (const short*)(wsf + OFF_WS + WS_D1);
    const short* wsD2 = (const short*)(wsf + OFF_WS + WS_D2);
    const short* wsD3 = (const short*)(wsf + OFF_WS + WS_D3);
    const short* cbs  = (const short*)(wsf + OFF_CBS);

    // partial-stat buffers live in whichever big buffer is dead at that stage
    double2* pE1 = (double2*)Bb;   // enc1: Bb free until enc2 writes it
    double2* pE2 = (double2*)Z;    // enc2: Z free until enc3 writes it
    double2* pD1 = (double2*)A;    // dec1: A free until dec2 writes it
    double2* pD2 = (double2*)Z;    // dec2: Z dead after dec1 consumed it

    prep_k<<<723, 256, 0, stream>>>(enc_w1, enc_w2, enc_w3, cb, wsf);

    // encoder
    fconv_k<80, 128, 3, false, true><<<dim3(512, 2), 256, 0, stream>>>(
        x, wsE1, enc_b1, nullptr, A, pE1);
    stats_k<<<128, 256, 0, stream>>>(pE1, bn1_g, bn1_b, st);
    fconv_k<128, 256, 3, true, true><<<dim3(512, 4), 256, 0, stream>>>(
        A, wsE2, enc_b2, st, Bb, pE2);
    stats_k<<<256, 256, 0, stream>>>(pE2, bn2_g, bn2_b, st);
    fconv_k<256, 64, 1, true, false><<<dim3(1024, 1), 256, 0, stream>>>(
        Bb, wsE3, enc_b3, st, Z, nullptr);

    // decoder splits overwrite (now-dead) encoder splits
    prep2_k<<<696, 256, 0, stream>>>(dec_w1, dec_w2, dec_w3, wsf);

    // vector quantizer
    vq_k<<<1024, 256, 0, stream>>>(Z, cb, cbs, wsf + OFF_C2, Z,
                                   outf + 5242881, lossp);
    fin_k<<<1, 64, 0, stream>>>(lossp, outf + 5242880);

    // decoder
    fconv_k<64, 256, 3, false, true><<<dim3(512, 4), 256, 0, stream>>>(
        Z, wsD1, dec_b1, nullptr, Bb, pD1);
    stats_k<<<256, 256, 0, stream>>>(pD1, dbn1_g, dbn1_b, st);
    fconv_k<256, 128, 3, true, true><<<dim3(512, 2), 256, 0, stream>>>(
        Bb, wsD2, dec_b2, st, A, pD2);
    stats_k<<<128, 256, 0, stream>>>(pD2, dbn2_g, dbn2_b, st);
    fconv_k<128, 80, 3, true, false><<<dim3(512, 2), 256, 0, stream>>>(
        A, wsD3, dec_b3, st, outf, nullptr);
}

// Round 6
// 482.512 us; speedup vs baseline: 1.1468x; 1.0514x over previous
//
#include <hip/hip_runtime.h>
#include <math.h>

#define N_B 16
#define T_LEN 4096

typedef float f32x4  __attribute__((ext_vector_type(4)));
typedef _Float16 half8 __attribute__((ext_vector_type(8)));

struct LL { long a, b; };   // two ds_read_b64 (rows are 8B-aligned, stride 72B)

// ---- workspace layout (float offsets) ----
static const size_t OFF_A    = 0;            // 16*128*4096
static const size_t OFF_B    = 8388608;      // 16*256*4096
static const size_t OFF_Z    = 25165824;     // 16*64*4096
static const size_t OFF_WS   = 29360128;     // split-weight region
static const size_t OFF_CBS  = 29540352;     // codebook split (32768 floats)
static const size_t OFF_C2   = 29683712;
static const size_t OFF_ST   = 29684736;
static const size_t OFF_LOSS = 29685760;

// split-weight offsets (floats from OFF_WS); decoder reuses after enc convs
static const size_t WS_E1 = 0;        // 3*3*128*32 = 36864 floats
static const size_t WS_E2 = 36864;    // 4*3*256*32 = 98304 floats
static const size_t WS_E3 = 135168;   // 8*1*64*32  = 16384 floats -> 151552
static const size_t WS_D1 = 0;        // 2*3*256*32 = 49152 floats
static const size_t WS_D2 = 49152;    // 8*3*128*32 = 98304 floats
static const size_t WS_D3 = 147456;   // 4*3*80*32  = 30720 floats -> 178176

// scaled f16 split: v = hi + lo * 2^-12, error ~2^-24 relative (f32-grade).
__device__ inline void f2h2(float v, short& hi, short& lo) {
    _Float16 h = (_Float16)v;
    float r = (v - (float)h) * 4096.0f;
    _Float16 l = (_Float16)r;
    hi = __builtin_bit_cast(short, h);
    lo = __builtin_bit_cast(short, l);
}
__device__ inline float h2f(short s) {
    return (float)__builtin_bit_cast(_Float16, s);
}

// fill split-weight fragments: dst layout [(c*KS+k)*2+p][co][32 ci-shorts]
template<int C_IN, int C_OUT, int KS>
__device__ inline void wsplit_fill(const float* __restrict__ w,
                                   short* __restrict__ dst, int e) {
    int i  = e & 31;
    int r  = e >> 5;
    int co = r % C_OUT;
    int r2 = r / C_OUT;          // c*KS + k
    int k  = r2 % KS;
    int c  = r2 / KS;
    int ci = c * 32 + i;
    float v = (ci < C_IN) ? w[((size_t)co * C_IN + ci) * KS + k] : 0.f;
    short h, l; f2h2(v, h, l);
    size_t base = ((size_t)(c * KS + k) * 2 * C_OUT + co) * 32 + i;
    dst[base] = h;
    dst[base + (size_t)C_OUT * 32] = l;
}

__global__ __launch_bounds__(256) void prep_k(
        const float* __restrict__ w1, const float* __restrict__ w2,
        const float* __restrict__ w3, const float* __restrict__ cb,
        float* wsf) {
    int e = blockIdx.x * 256 + threadIdx.x;
    if (e < 36864)        wsplit_fill<80, 128, 3>(w1, (short*)(wsf + OFF_WS + WS_E1), e);
    else if (e < 135168)  wsplit_fill<128, 256, 3>(w2, (short*)(wsf + OFF_WS + WS_E2), e - 36864);
    else if (e < 151552)  wsplit_fill<256, 64, 1>(w3, (short*)(wsf + OFF_WS + WS_E3), e - 135168);
    else if (e < 152064) {
        int c = e - 151552;
        const float* p = cb + (size_t)c * 64;
        double s = 0.0;
        for (int d = 0; d < 64; ++d) { double v = p[d]; s += v * v; }
        wsf[OFF_C2 + c] = (float)s;
    } else if (e < 184832) {
        // codebook split fragments (vq_k): [ks][plane][code][32 d-shorts]
        int e2   = e - 152064;
        int i    = e2 & 31;
        int r    = e2 >> 5;
        int code = r & 511;
        int ks   = r >> 9;
        float v  = cb[(size_t)code * 64 + ks * 32 + i];
        short h, l; f2h2(v, h, l);
        short* dst = (short*)(wsf + OFF_CBS);
        dst[((size_t)(ks * 2 + 0) * 512 + code) * 32 + i] = h;
        dst[((size_t)(ks * 2 + 1) * 512 + code) * 32 + i] = l;
    } else if (e == 184832) {
        *(double*)(wsf + OFF_LOSS) = 0.0;
    }
}

__global__ __launch_bounds__(256) void prep2_k(
        const float* __restrict__ wd1, const float* __restrict__ wd2,
        const float* __restrict__ wd3, float* wsf) {
    int e = blockIdx.x * 256 + threadIdx.x;
    if (e < 49152)        wsplit_fill<64, 256, 3>(wd1, (short*)(wsf + OFF_WS + WS_D1), e);
    else if (e < 147456)  wsplit_fill<256, 128, 3>(wd2, (short*)(wsf + OFF_WS + WS_D2), e - 49152);
    else if (e < 178176)  wsplit_fill<128, 80, 3>(wd3, (short*)(wsf + OFF_WS + WS_D3), e - 147456);
}

// ---- conv1d via scaled-f16 split MFMA 16x16x32 (r3 chassis) ----
// GEMM M=co, N=t, K=ci per tap. Block 64co x TT t; wave = 16co strip x TT t
// (r3-proven fastest structure: lean VGPR -> 34% occupancy).
// Maps (HW-verified r1-r5): A[m=lane&15][k=q*8+j], B[k=q*8+j][n=lane&15],
// D[m=q*4+r][n=lane&15].
// LDS: separate hi/lo planes, row stride 36 shorts (r4/r5-proven ~2e6 confl).
// XCD-grouped swizzle: round-robin dispatch (b -> XCD b%8); all NCO co-blocks
// of a tile get consecutive b on one XCD -> x-tile fetched once, L2-shared.
// Fused BN-stat partials: one double2 per (block, co) -> part[coi*NTL+tl][co].
template<int C_IN, int C_OUT, int KS, bool BN_IN, bool STATS>
__global__ __launch_bounds__(256, 3) void fconv_k(
        const float* __restrict__ x, const short* __restrict__ wsp,
        const float* __restrict__ bias, const float2* __restrict__ stats,
        float* __restrict__ out, double2* __restrict__ part) {
    constexpr int NCH   = (C_IN + 31) / 32;
    constexpr int NCO   = (C_OUT + 63) / 64;
    constexpr int HALO  = KS / 2;
    constexpr int TT    = (KS == 1) ? 64 : 128;
    constexpr int NTT   = TT / 16;               // 8 (KS=3) or 4 (KS=1)
    constexpr int NTILE = T_LEN / TT;
    constexpr int NTL   = N_B * NTILE;           // tiles total (512 or 1024)
    constexpr int XR    = TT + KS - 1;
    constexpr int RS    = 36;                    // shorts/row (72B, 18 dwords)
    constexpr int TQ    = TT / 4;

    __shared__ __align__(16) short xh[XR * RS];
    __shared__ __align__(16) short xl[XR * RS];
    __shared__ int okf;

    const int tid  = threadIdx.x;
    const int lane = tid & 63;
    const int wv   = tid >> 6;
    const int ln   = lane & 15;
    const int q    = lane >> 4;

    // XCD-grouped swizzle (NTL % 8 == 0 holds for all shapes here)
    const int b    = blockIdx.x;
    const int xcd  = b & 7;
    const int jj   = b >> 3;
    const int coi  = jj % NCO;
    const int tl   = (jj / NCO) + (NTL / 8) * xcd;
    const int n    = tl / NTILE;
    const int t0   = (tl % NTILE) * TT;
    const int co0  = coi * 64;
    const int co_l = co0 + wv * 16 + ln;         // A-fragment row for this lane

    // ---- integer probe for 16x16x32 f16 layout (HW-verified r1-r5) ----
    bool ok = true;
    {
        half8 pa, pb;
#pragma unroll
        for (int j = 0; j < 8; ++j) {
            int kk = q * 8 + j;
            pa[j] = (_Float16)(float)(ln + 2 * kk);
            pb[j] = (_Float16)(float)(ln + 3 * kk);
        }
        f32x4 pd = {0.f, 0.f, 0.f, 0.f};
        pd = __builtin_amdgcn_mfma_f32_16x16x32_f16(pa, pb, pd, 0, 0, 0);
#pragma unroll
        for (int r = 0; r < 4; ++r) {
            int m = q * 4 + r;
            float e = (float)(32 * m * ln + 1488 * m + 992 * ln + 62496);
            if (pd[r] != e) ok = false;
        }
    }
    if (tid == 0) okf = 1;
    __syncthreads();
    if (!ok) okf = 0;
    __syncthreads();
    const bool okp = (okf != 0);

    f32x4 a0[NTT], a1[NTT];
#pragma unroll
    for (int tt = 0; tt < NTT; ++tt)
#pragma unroll
        for (int i = 0; i < 4; ++i) { a0[tt][i] = 0.f; a1[tt][i] = 0.f; }

#pragma unroll 1
    for (int c = 0; c < NCH; ++c) {
        // ---- w fragments: issued before staging so latency hides under it ----
        half8 ah[KS], al[KS];
        {
            half8 z8 = {0, 0, 0, 0, 0, 0, 0, 0};
#pragma unroll
            for (int k = 0; k < KS; ++k) {
                const short* wp = wsp
                    + ((size_t)(c * KS + k) * 2 * C_OUT + co_l) * 32 + q * 8;
                ah[k] = (co_l < C_OUT) ? *(const half8*)wp : z8;
                al[k] = (co_l < C_OUT) ? *(const half8*)(wp + (size_t)C_OUT * 32) : z8;
            }
        }

        __syncthreads();
        // ---- stage x tile into split planes ----
        for (int e = tid; e < 32 * TQ; e += 256) {
            const int ci  = e / TQ;
            const int tq  = e % TQ;
            const int cig = c * 32 + ci;
            float v[4] = {0.f, 0.f, 0.f, 0.f};
            if (cig < C_IN) {
                const float* xp = x + ((size_t)(n * C_IN + cig)) * T_LEN + t0 + tq;
#pragma unroll
                for (int j = 0; j < 4; ++j) v[j] = xp[TQ * j];
                if (BN_IN) {
                    float2 sst = stats[cig];
#pragma unroll
                    for (int j = 0; j < 4; ++j) v[j] = fmaxf(fmaf(v[j], sst.x, sst.y), 0.f);
                }
            }
#pragma unroll
            for (int j = 0; j < 4; ++j) {
                short h, l; f2h2(v[j], h, l);
                const int row = HALO + tq + TQ * j;
                xh[row * RS + ci] = h;
                xl[row * RS + ci] = l;
            }
        }
        if (KS == 3) {
            if (tid < 64) {
                const int ci   = tid & 31;
                const int side = tid >> 5;
                const int cig  = c * 32 + ci;
                const int gt   = side ? (t0 + TT) : (t0 - 1);
                float vv = 0.f;
                if (cig < C_IN && gt >= 0 && gt < T_LEN) {
                    vv = x[((size_t)(n * C_IN + cig)) * T_LEN + gt];
                    if (BN_IN) {
                        float2 sst = stats[cig];
                        vv = fmaxf(fmaf(vv, sst.x, sst.y), 0.f);
                    }
                }
                short h, l; f2h2(vv, h, l);
                const int row = side ? (XR - 1) : 0;
                xh[row * RS + ci] = h;
                xl[row * RS + ci] = l;
            }
        }
        __syncthreads();

        if (okp) {
#pragma unroll
            for (int k = 0; k < KS; ++k) {
#pragma unroll
                for (int tt = 0; tt < NTT; ++tt) {
                    const int row = tt * 16 + ln + k;
                    const short* ph = &xh[row * RS + q * 8];
                    const short* pl = &xl[row * RS + q * 8];
                    LL th, tlv;
                    th.a  = *(const long*)ph; th.b  = *(const long*)(ph + 4);
                    tlv.a = *(const long*)pl; tlv.b = *(const long*)(pl + 4);
                    half8 bh = __builtin_bit_cast(half8, th);
                    half8 bl = __builtin_bit_cast(half8, tlv);
                    a0[tt] = __builtin_amdgcn_mfma_f32_16x16x32_f16(ah[k], bh, a0[tt], 0, 0, 0);
                    a1[tt] = __builtin_amdgcn_mfma_f32_16x16x32_f16(ah[k], bl, a1[tt], 0, 0, 0);
                    a1[tt] = __builtin_amdgcn_mfma_f32_16x16x32_f16(al[k], bh, a1[tt], 0, 0, 0);
                }
            }
        } else {
            // correctness fallback from the same tiles, same D-map
#pragma unroll 1
            for (int k = 0; k < KS; ++k)
#pragma unroll 1
                for (int ci = 0; ci < 32; ++ci) {
                    float wr_[4];
#pragma unroll
                    for (int r = 0; r < 4; ++r) {
                        const int co = co0 + wv * 16 + q * 4 + r;
                        float vv = 0.f;
                        if (co < C_OUT) {
                            const size_t bb =
                                ((size_t)(c * KS + k) * 2 * C_OUT + co) * 32 + ci;
                            vv = h2f(wsp[bb])
                               + h2f(wsp[bb + (size_t)C_OUT * 32]) * 0.000244140625f;
                        }
                        wr_[r] = vv;
                    }
#pragma unroll
                    for (int tt = 0; tt < NTT; ++tt) {
                        const int row = tt * 16 + ln + k;
                        const float xv = h2f(xh[row * RS + ci])
                                       + h2f(xl[row * RS + ci]) * 0.000244140625f;
#pragma unroll
                        for (int r = 0; r < 4; ++r)
                            a0[tt][r] = fmaf(wr_[r], xv, a0[tt][r]);
                    }
                }
        }
    }

    // ---- epilogue: store + fused BN-stat partials ----
    const int plinear = coi * NTL + tl;
#pragma unroll
    for (int r = 0; r < 4; ++r) {
        const int co = co0 + wv * 16 + q * 4 + r;
        double s1 = 0.0, s2 = 0.0;
        if (co < C_OUT) {
            const float bv = bias[co];
            float* op = out + ((size_t)(n * C_OUT + co)) * T_LEN + t0 + ln;
#pragma unroll
            for (int tt = 0; tt < NTT; ++tt) {
                const float v = fmaf(a1[tt][r], 0.000244140625f, a0[tt][r]) + bv;
                op[tt * 16] = v;
                if (STATS) { s1 += (double)v; s2 += (double)v * (double)v; }
            }
        }
        if (STATS) {
#pragma unroll
            for (int off = 1; off <= 8; off <<= 1) {
                s1 += __shfl_xor(s1, off);
                s2 += __shfl_xor(s2, off);
            }
            if (ln == 0)
                part[(size_t)plinear * 64 + wv * 16 + q * 4 + r] =
                    make_double2(s1, s2);
        }
    }
}

// ---- BN stats: reduce 512 per-block partials per channel, finalize ----
__global__ __launch_bounds__(256) void stats_k(
        const double2* __restrict__ part, const float* __restrict__ g,
        const float* __restrict__ b, float2* __restrict__ stats) {
    const int c = blockIdx.x;
    const int tid = threadIdx.x;
    double s1 = 0.0, s2 = 0.0;
    for (int j = tid; j < 512; j += 256) {
        double2 v = part[((size_t)(c >> 6) * 512 + j) * 64 + (c & 63)];
        s1 += v.x; s2 += v.y;
    }
    __shared__ double r1[256], r2[256];
    r1[tid] = s1; r2[tid] = s2;
    __syncthreads();
    for (int s = 128; s > 0; s >>= 1) {
        if (tid < s) { r1[tid] += r1[tid + s]; r2[tid] += r2[tid + s]; }
        __syncthreads();
    }
    if (tid == 0) {
        double m   = r1[0] / 65536.0;
        double var = r2[0] / 65536.0 - m * m;
        double sc  = (double)g[c] / sqrt(var + 1e-5);
        stats[c] = make_float2((float)sc, (float)((double)b[c] - m * sc));
    }
}

// ---- VQ via scaled-f16 split MFMA (16x16x32, r3-proven) ----
__global__ __launch_bounds__(256) void vq_k(
        const float* __restrict__ z, const float* __restrict__ cb,
        const short* __restrict__ cbs, const float* __restrict__ c2,
        float* __restrict__ q, float* __restrict__ idx_out,
        double* __restrict__ loss) {
    __shared__ __align__(16) float zs[64 * 68];
    __shared__ __align__(16) short zh[64 * 136];
    __shared__ float  c2s[512];
    __shared__ float  szf_s[64];
    __shared__ int    idxs[64];
    __shared__ double dred[256];

    const int tid  = threadIdx.x;
    const int lane = tid & 63;
    const int wv   = tid >> 6;
    const int ln   = lane & 15;
    const int q4   = lane >> 4;
    const int n    = blockIdx.x >> 6;
    const int t0   = (blockIdx.x & 63) * 64;

    for (int e = tid; e < 512; e += 256) c2s[e] = c2[e];
    for (int e = tid; e < 1024; e += 256) {
        const int d  = e >> 4;
        const int tq = e & 15;
        const float* zp = z + ((size_t)(n * 64 + d)) * T_LEN + t0 + tq;
        const int ks = d >> 5, i = d & 31;
#pragma unroll
        for (int j = 0; j < 4; ++j) {
            const int t = tq + 16 * j;
            float v = zp[16 * j];
            zs[t * 68 + d] = v;
            short h, l; f2h2(v, h, l);
            zh[t * 136 + (ks * 2 + 0) * 32 + i] = h;
            zh[t * 136 + (ks * 2 + 1) * 32 + i] = l;
        }
    }
    __syncthreads();
    if (tid < 64) {
        double s = 0.0;
        const float* zr = &zs[tid * 68];
        for (int d = 0; d < 64; ++d) { double v = zr[d]; s += v * v; }
        szf_s[tid] = (float)s;
    }
    __syncthreads();

    const short* zr = &zh[(wv * 16 + ln) * 136 + q4 * 8];
    const half8 bh0 = *(const half8*)&zr[0];
    const half8 bl0 = *(const half8*)&zr[32];
    const half8 bh1 = *(const half8*)&zr[64];
    const half8 bl1 = *(const half8*)&zr[96];
    const float As  = szf_s[wv * 16 + ln];

    float bs = 3.0e38f;
    int   bi = 1 << 30;

#pragma unroll 4
    for (int ct = 0; ct < 32; ++ct) {
        const short* ap = cbs + ((size_t)(ct * 16 + ln)) * 32 + q4 * 8;
        const half8 ah0 = *(const half8*)&ap[0];
        const half8 al0 = *(const half8*)&ap[512 * 32];
        const half8 ah1 = *(const half8*)&ap[2 * 512 * 32];
        const half8 al1 = *(const half8*)&ap[3 * 512 * 32];
        f32x4 a0 = {0.f, 0.f, 0.f, 0.f};
        f32x4 a1 = {0.f, 0.f, 0.f, 0.f};
        a0 = __builtin_amdgcn_mfma_f32_16x16x32_f16(ah0, bh0, a0, 0, 0, 0);
        a1 = __builtin_amdgcn_mfma_f32_16x16x32_f16(ah0, bl0, a1, 0, 0, 0);
        a1 = __builtin_amdgcn_mfma_f32_16x16x32_f16(al0, bh0, a1, 0, 0, 0);
        a0 = __builtin_amdgcn_mfma_f32_16x16x32_f16(ah1, bh1, a0, 0, 0, 0);
        a1 = __builtin_amdgcn_mfma_f32_16x16x32_f16(ah1, bl1, a1, 0, 0, 0);
        a1 = __builtin_amdgcn_mfma_f32_16x16x32_f16(al1, bh1, a1, 0, 0, 0);
#pragma unroll
        for (int r = 0; r < 4; ++r) {
            const int code = ct * 16 + q4 * 4 + r;
            const float m32 = fmaf(a1[r], 0.000244140625f, a0[r]);
            const float A   = As + c2s[code];
            const float s   = A - 2.0f * m32;
            if (s < bs || (s == bs && code < bi)) { bs = s; bi = code; }
        }
    }
#pragma unroll
    for (int off = 16; off <= 32; off <<= 1) {
        const float os = __shfl_xor(bs, off);
        const int   oi = __shfl_xor(bi, off);
        if (os < bs || (os == bs && oi < bi)) { bs = os; bi = oi; }
    }
    if (q4 == 0) {
        const int t = wv * 16 + ln;
        idxs[t] = bi;
        idx_out[(size_t)n * T_LEN + t0 + t] = (float)bi;
    }
    __syncthreads();

    {
        const int g = tid >> 6, t = tid & 63;
        const int bi2 = idxs[t];
        double ls = 0.0;
        for (int dd = 0; dd < 16; ++dd) {
            const int d = g * 16 + dd;
            const float qv = cb[(size_t)bi2 * 64 + d];
            const float zv = zs[t * 68 + d];
            const double df = (double)qv - (double)zv;
            ls += df * df;
            q[((size_t)(n * 64 + d)) * T_LEN + t0 + t] = qv;
        }
        dred[tid] = ls;
    }
    __syncthreads();
    for (int s = 128; s > 0; s >>= 1) {
        if (tid < s) dred[tid] += dred[tid + s];
        __syncthreads();
    }
    if (tid == 0) atomicAdd(loss, dred[0]);
}

__global__ void fin_k(const double* __restrict__ loss, float* __restrict__ out) {
    if (threadIdx.x == 0 && blockIdx.x == 0)
        out[0] = (float)(1.25 * (*loss) / 4194304.0);
}

extern "C" void kernel_launch(void* const* d_in, const int* in_sizes, int n_in,
                              void* d_out, int out_size, void* d_ws, size_t ws_size,
                              hipStream_t stream) {
    const float* x      = (const float*)d_in[0];
    const float* enc_w1 = (const float*)d_in[1];
    const float* enc_b1 = (const float*)d_in[2];
    const float* bn1_g  = (const float*)d_in[3];
    const float* bn1_b  = (const float*)d_in[4];
    const float* enc_w2 = (const float*)d_in[5];
    const float* enc_b2 = (const float*)d_in[6];
    const float* bn2_g  = (const float*)d_in[7];
    const float* bn2_b  = (const float*)d_in[8];
    const float* enc_w3 = (const float*)d_in[9];
    const float* enc_b3 = (const float*)d_in[10];
    const float* cb     = (const float*)d_in[11];
    const float* dec_w1 = (const float*)d_in[12];
    const float* dec_b1 = (const float*)d_in[13];
    const float* dbn1_g = (const float*)d_in[14];
    const float* dbn1_b = (const float*)d_in[15];
    const float* dec_w2 = (const float*)d_in[16];
    const float* dec_b2 = (const float*)d_in[17];
    const float* dbn2_g = (const float*)d_in[18];
    const float* dbn2_b = (const float*)d_in[19];
    const float* dec_w3 = (const float*)d_in[20];
    const float* dec_b3 = (const float*)d_in[21];

    float* wsf   = (float*)d_ws;
    float* outf  = (float*)d_out;
    float* A     = wsf + OFF_A;
    float* Bb    = wsf + OFF_B;
    float* Z     = wsf + OFF_Z;
    float2* st   = (float2*)(wsf + OFF_ST);
    double* lossp = (double*)(wsf + OFF_LOSS);

    const short* wsE1 = (const short*)(wsf + OFF_WS + WS_E1);
    const short* wsE2 = (const short*)(wsf + OFF_WS + WS_E2);
    const short* wsE3 = (const short*)(wsf + OFF_WS + WS_E3);
    const short* wsD1 = (const short*)(wsf + OFF_WS + WS_D1);
    const short* wsD2 = (const short*)(wsf + OFF_WS + WS_D2);
    const short* wsD3 = (const short*)(wsf + OFF_WS + WS_D3);
    const short* cbs  = (const short*)(wsf + OFF_CBS);

    // partial-stat buffers live in whichever big buffer is dead at that stage
    double2* pE1 = (double2*)Bb;   // enc1: Bb free until enc2 writes it
    double2* pE2 = (double2*)Z;    // enc2: Z free until enc3 writes it
    double2* pD1 = (double2*)A;    // dec1: A free until dec2 writes it
    double2* pD2 = (double2*)Z;    // dec2: Z dead after dec1 consumed it

    prep_k<<<723, 256, 0, stream>>>(enc_w1, enc_w2, enc_w3, cb, wsf);

    // encoder (1D grids: N_B*NTILE*NCO, XCD-swizzled in-kernel)
    fconv_k<80, 128, 3, false, true><<<1024, 256, 0, stream>>>(
        x, wsE1, enc_b1, nullptr, A, pE1);
    stats_k<<<128, 256, 0, stream>>>(pE1, bn1_g, bn1_b, st);
    fconv_k<128, 256, 3, true, true><<<2048, 256, 0, stream>>>(
        A, wsE2, enc_b2, st, Bb, pE2);
    stats_k<<<256, 256, 0, stream>>>(pE2, bn2_g, bn2_b, st);
    fconv_k<256, 64, 1, true, false><<<1024, 256, 0, stream>>>(
        Bb, wsE3, enc_b3, st, Z, nullptr);

    // decoder splits overwrite (now-dead) encoder splits
    prep2_k<<<696, 256, 0, stream>>>(dec_w1, dec_w2, dec_w3, wsf);

    // vector quantizer
    vq_k<<<1024, 256, 0, stream>>>(Z, cb, cbs, wsf + OFF_C2, Z,
                                   outf + 5242881, lossp);
    fin_k<<<1, 64, 0, stream>>>(lossp, outf + 5242880);

    // decoder
    fconv_k<64, 256, 3, false, true><<<2048, 256, 0, stream>>>(
        Z, wsD1, dec_b1, nullptr, Bb, pD1);
    stats_k<<<256, 256, 0, stream>>>(pD1, dbn1_g, dbn1_b, st);
    fconv_k<256, 128, 3, true, true><<<1024, 256, 0, stream>>>(
        Bb, wsD2, dec_b2, st, A, pD2);
    stats_k<<<128, 256, 0, stream>>>(pD2, dbn2_g, dbn2_b, st);
    fconv_k<128, 80, 3, true, false><<<1024, 256, 0, stream>>>(
        A, wsD3, dec_b3, st, outf, nullptr);
}

// Round 7
// 380.286 us; speedup vs baseline: 1.4551x; 1.2688x over previous
//
#include <hip/hip_runtime.h>
#include <math.h>

#define N_B 16
#define T_LEN 4096

typedef float f32x4  __attribute__((ext_vector_type(4)));
typedef _Float16 half8 __attribute__((ext_vector_type(8)));

// ---- workspace layout (float offsets) ----
static const size_t OFF_A    = 0;            // 16*128*4096
static const size_t OFF_B    = 8388608;      // 16*256*4096
static const size_t OFF_Z    = 25165824;     // 16*64*4096
static const size_t OFF_WS   = 29360128;     // split-weight region
static const size_t OFF_CBS  = 29540352;     // codebook split (32768 floats)
static const size_t OFF_C2   = 29683712;
static const size_t OFF_ST   = 29684736;
static const size_t OFF_LOSS = 29685760;

// split-weight offsets (floats from OFF_WS); decoder reuses after enc convs
static const size_t WS_E1 = 0;        // 3*3*128*32 = 36864 floats
static const size_t WS_E2 = 36864;    // 4*3*256*32 = 98304 floats
static const size_t WS_E3 = 135168;   // 8*1*64*32  = 16384 floats -> 151552
static const size_t WS_D1 = 0;        // 2*3*256*32 = 49152 floats
static const size_t WS_D2 = 49152;    // 8*3*128*32 = 98304 floats
static const size_t WS_D3 = 147456;   // 4*3*80*32  = 30720 floats -> 178176

// scaled f16 split: v = hi + lo * 2^-12, error ~2^-24 relative (f32-grade).
__device__ inline void f2h2(float v, short& hi, short& lo) {
    _Float16 h = (_Float16)v;
    float r = (v - (float)h) * 4096.0f;
    _Float16 l = (_Float16)r;
    hi = __builtin_bit_cast(short, h);
    lo = __builtin_bit_cast(short, l);
}
__device__ inline float h2f(short s) {
    return (float)__builtin_bit_cast(_Float16, s);
}

// fill split-weight fragments: dst layout [(c*KS+k)*2+p][co][32 ci-shorts]
template<int C_IN, int C_OUT, int KS>
__device__ inline void wsplit_fill(const float* __restrict__ w,
                                   short* __restrict__ dst, int e) {
    int i  = e & 31;
    int r  = e >> 5;
    int co = r % C_OUT;
    int r2 = r / C_OUT;          // c*KS + k
    int k  = r2 % KS;
    int c  = r2 / KS;
    int ci = c * 32 + i;
    float v = (ci < C_IN) ? w[((size_t)co * C_IN + ci) * KS + k] : 0.f;
    short h, l; f2h2(v, h, l);
    size_t base = ((size_t)(c * KS + k) * 2 * C_OUT + co) * 32 + i;
    dst[base] = h;
    dst[base + (size_t)C_OUT * 32] = l;
}

__global__ __launch_bounds__(256) void prep_k(
        const float* __restrict__ w1, const float* __restrict__ w2,
        const float* __restrict__ w3, const float* __restrict__ cb,
        float* wsf) {
    int e = blockIdx.x * 256 + threadIdx.x;
    if (e < 36864)        wsplit_fill<80, 128, 3>(w1, (short*)(wsf + OFF_WS + WS_E1), e);
    else if (e < 135168)  wsplit_fill<128, 256, 3>(w2, (short*)(wsf + OFF_WS + WS_E2), e - 36864);
    else if (e < 151552)  wsplit_fill<256, 64, 1>(w3, (short*)(wsf + OFF_WS + WS_E3), e - 135168);
    else if (e < 152064) {
        int c = e - 151552;
        const float* p = cb + (size_t)c * 64;
        double s = 0.0;
        for (int d = 0; d < 64; ++d) { double v = p[d]; s += v * v; }
        wsf[OFF_C2 + c] = (float)s;
    } else if (e < 184832) {
        // codebook split fragments (vq_k): [ks][plane][code][32 d-shorts]
        int e2   = e - 152064;
        int i    = e2 & 31;
        int r    = e2 >> 5;
        int code = r & 511;
        int ks   = r >> 9;
        float v  = cb[(size_t)code * 64 + ks * 32 + i];
        short h, l; f2h2(v, h, l);
        short* dst = (short*)(wsf + OFF_CBS);
        dst[((size_t)(ks * 2 + 0) * 512 + code) * 32 + i] = h;
        dst[((size_t)(ks * 2 + 1) * 512 + code) * 32 + i] = l;
    } else if (e == 184832) {
        *(double*)(wsf + OFF_LOSS) = 0.0;
    }
}

__global__ __launch_bounds__(256) void prep2_k(
        const float* __restrict__ wd1, const float* __restrict__ wd2,
        const float* __restrict__ wd3, float* wsf) {
    int e = blockIdx.x * 256 + threadIdx.x;
    if (e < 49152)        wsplit_fill<64, 256, 3>(wd1, (short*)(wsf + OFF_WS + WS_D1), e);
    else if (e < 147456)  wsplit_fill<256, 128, 3>(wd2, (short*)(wsf + OFF_WS + WS_D2), e - 49152);
    else if (e < 178176)  wsplit_fill<128, 80, 3>(wd3, (short*)(wsf + OFF_WS + WS_D3), e - 147456);
}

// ---- conv1d via scaled-f16 split MFMA (exact r3 chassis, proven 60us) ----
// GEMM M=co, N=t, K=ci per k-tap. Block: 64co x TT t, 4 waves (wave=16co strip).
// Maps (HW-verified r1-r6): A[m=lane&15][k=q*8+j], B[k=q*8+j][n=lane&15],
// D[m=q*4+r][n=lane&15].  acc0 += ah*bh ; acc1 += ah*bl + al*bh.
// Only change vs r3: STATS epilogue (f32 partial sums, 2 VGPR + 8 shuffles).
template<int C_IN, int C_OUT, int KS, bool BN_IN, bool STATS>
__global__ __launch_bounds__(256, 3) void fconv_k(
        const float* __restrict__ x, const short* __restrict__ wsp,
        const float* __restrict__ bias, const float2* __restrict__ stats,
        float* __restrict__ out, float2* __restrict__ part) {
    constexpr int NCH  = (C_IN + 31) / 32;
    constexpr int HALO = KS / 2;
    constexpr int TT   = (KS == 1) ? 64 : 128;   // t-tile
    constexpr int NTT  = TT / 16;                // MFMA t-subtiles
    constexpr int NTILE = T_LEN / TT;
    constexpr int XR   = TT + KS - 1;
    constexpr int RS   = 72;                     // shorts/row (144B, 16B-aligned)
    constexpr int LO   = 40;                     // lo-plane offset within row
    constexpr int TQ   = TT / 4;                 // t-stride for 4-way load

    __shared__ __align__(16) short xs[XR * RS];

    const int tid  = threadIdx.x;
    const int lane = tid & 63;
    const int wv   = tid >> 6;
    const int ln   = lane & 15;
    const int q    = lane >> 4;

    const int n    = blockIdx.x / NTILE;
    const int t0   = (blockIdx.x % NTILE) * TT;
    const int co0  = blockIdx.y * 64;
    const int co_l = co0 + wv * 16 + ln;         // A-fragment row for this lane

    f32x4 a0[NTT], a1[NTT];
#pragma unroll
    for (int tt = 0; tt < NTT; ++tt)
#pragma unroll
        for (int i = 0; i < 4; ++i) { a0[tt][i] = 0.f; a1[tt][i] = 0.f; }

#pragma unroll 1
    for (int c = 0; c < NCH; ++c) {
        // ---- w fragments: direct global loads (L2-hot, coalesced 16B) ----
        half8 ah[KS], al[KS];
        {
            half8 z = {0, 0, 0, 0, 0, 0, 0, 0};
#pragma unroll
            for (int k = 0; k < KS; ++k) {
                const short* wp = wsp
                    + ((size_t)(c * KS + k) * 2 * C_OUT + co_l) * 32 + q * 8;
                ah[k] = (co_l < C_OUT) ? *(const half8*)wp : z;
                al[k] = (co_l < C_OUT) ? *(const half8*)(wp + (size_t)C_OUT * 32) : z;
            }
        }

        __syncthreads();
        // ---- stage x tile [t-row][ci] with split planes ----
        for (int e = tid; e < 32 * TQ; e += 256) {
            const int ci  = e / TQ;
            const int tq  = e % TQ;
            const int cig = c * 32 + ci;
            float v[4] = {0.f, 0.f, 0.f, 0.f};
            if (cig < C_IN) {
                const float* xp = x + ((size_t)(n * C_IN + cig)) * T_LEN + t0 + tq;
#pragma unroll
                for (int j = 0; j < 4; ++j) v[j] = xp[TQ * j];
                if (BN_IN) {
                    float2 s = stats[cig];
#pragma unroll
                    for (int j = 0; j < 4; ++j) v[j] = fmaxf(fmaf(v[j], s.x, s.y), 0.f);
                }
            }
#pragma unroll
            for (int j = 0; j < 4; ++j) {
                short h, l; f2h2(v[j], h, l);
                short* p = &xs[(HALO + tq + TQ * j) * RS + ci];
                p[0]  = h;
                p[LO] = l;
            }
        }
        if (KS == 3) {
            if (tid < 64) {
                const int ci   = tid & 31;
                const int side = tid >> 5;
                const int cig  = c * 32 + ci;
                const int gt   = side ? (t0 + TT) : (t0 - 1);
                float v = 0.f;
                if (cig < C_IN && gt >= 0 && gt < T_LEN) {
                    v = x[((size_t)(n * C_IN + cig)) * T_LEN + gt];
                    if (BN_IN) {
                        float2 s = stats[cig];
                        v = fmaxf(fmaf(v, s.x, s.y), 0.f);
                    }
                }
                short h, l; f2h2(v, h, l);
                short* p = &xs[(side ? (XR - 1) : 0) * RS + ci];
                p[0] = h; p[LO] = l;
            }
        }
        __syncthreads();

        // ---- MFMA: 3-product split (b128 LDS reads, r3-proven) ----
#pragma unroll
        for (int k = 0; k < KS; ++k) {
#pragma unroll
            for (int tt = 0; tt < NTT; ++tt) {
                const short* xr = &xs[(tt * 16 + ln + k) * RS + q * 8];
                half8 bh = *(const half8*)&xr[0];
                half8 bl = *(const half8*)&xr[LO];
                a0[tt] = __builtin_amdgcn_mfma_f32_16x16x32_f16(ah[k], bh, a0[tt], 0, 0, 0);
                a1[tt] = __builtin_amdgcn_mfma_f32_16x16x32_f16(ah[k], bl, a1[tt], 0, 0, 0);
                a1[tt] = __builtin_amdgcn_mfma_f32_16x16x32_f16(al[k], bh, a1[tt], 0, 0, 0);
            }
        }
    }

    // epilogue: lane reg r -> D[co = co0+wv*16+q*4+r][t = t0+tt*16+ln]
    // + optional fused BN partial sums (f32, 16-lane shfl reduce over ln)
    const int plinear = blockIdx.y * (N_B * NTILE) + blockIdx.x;
#pragma unroll
    for (int r = 0; r < 4; ++r) {
        const int co = co0 + wv * 16 + q * 4 + r;
        float s1 = 0.f, s2 = 0.f;
        if (co < C_OUT) {
            const float bv = bias[co];
            float* op = out + ((size_t)(n * C_OUT + co)) * T_LEN + t0 + ln;
#pragma unroll
            for (int tt = 0; tt < NTT; ++tt) {
                const float v = fmaf(a1[tt][r], 0.000244140625f, a0[tt][r]) + bv;
                op[tt * 16] = v;
                if (STATS) { s1 += v; s2 = fmaf(v, v, s2); }
            }
        }
        if (STATS) {
#pragma unroll
            for (int off = 1; off <= 8; off <<= 1) {
                s1 += __shfl_xor(s1, off);
                s2 += __shfl_xor(s2, off);
            }
            if (ln == 0)
                part[(size_t)plinear * 64 + wv * 16 + q * 4 + r] =
                    make_float2(s1, s2);
        }
    }
}

// ---- BN stats: reduce 512 per-block float2 partials per channel (f64) ----
__global__ __launch_bounds__(256) void stats_k(
        const float2* __restrict__ part, const float* __restrict__ g,
        const float* __restrict__ b, float2* __restrict__ stats) {
    const int c = blockIdx.x;
    const int tid = threadIdx.x;
    double s1 = 0.0, s2 = 0.0;
    for (int j = tid; j < 512; j += 256) {
        float2 v = part[((size_t)(c >> 6) * 512 + j) * 64 + (c & 63)];
        s1 += (double)v.x; s2 += (double)v.y;
    }
    __shared__ double r1[256], r2[256];
    r1[tid] = s1; r2[tid] = s2;
    __syncthreads();
    for (int s = 128; s > 0; s >>= 1) {
        if (tid < s) { r1[tid] += r1[tid + s]; r2[tid] += r2[tid + s]; }
        __syncthreads();
    }
    if (tid == 0) {
        double m   = r1[0] / 65536.0;
        double var = r2[0] / 65536.0 - m * m;
        double sc  = (double)g[c] / sqrt(var + 1e-5);
        stats[c] = make_float2((float)sc, (float)((double)b[c] - m * sc));
    }
}

// ---- VQ via scaled-f16 split MFMA (16x16x32, r3-proven, verbatim) ----
__global__ __launch_bounds__(256) void vq_k(
        const float* __restrict__ z, const float* __restrict__ cb,
        const short* __restrict__ cbs, const float* __restrict__ c2,
        float* __restrict__ q, float* __restrict__ idx_out,
        double* __restrict__ loss) {
    __shared__ __align__(16) float zs[64 * 68];
    __shared__ __align__(16) short zh[64 * 136];
    __shared__ float  c2s[512];
    __shared__ float  szf_s[64];
    __shared__ int    idxs[64];
    __shared__ double dred[256];

    const int tid  = threadIdx.x;
    const int lane = tid & 63;
    const int wv   = tid >> 6;
    const int ln   = lane & 15;
    const int q4   = lane >> 4;
    const int n    = blockIdx.x >> 6;
    const int t0   = (blockIdx.x & 63) * 64;

    for (int e = tid; e < 512; e += 256) c2s[e] = c2[e];
    for (int e = tid; e < 1024; e += 256) {
        const int d  = e >> 4;
        const int tq = e & 15;
        const float* zp = z + ((size_t)(n * 64 + d)) * T_LEN + t0 + tq;
        const int ks = d >> 5, i = d & 31;
#pragma unroll
        for (int j = 0; j < 4; ++j) {
            const int t = tq + 16 * j;
            float v = zp[16 * j];
            zs[t * 68 + d] = v;
            short h, l; f2h2(v, h, l);
            zh[t * 136 + (ks * 2 + 0) * 32 + i] = h;
            zh[t * 136 + (ks * 2 + 1) * 32 + i] = l;
        }
    }
    __syncthreads();
    if (tid < 64) {
        double s = 0.0;
        const float* zr = &zs[tid * 68];
        for (int d = 0; d < 64; ++d) { double v = zr[d]; s += v * v; }
        szf_s[tid] = (float)s;
    }
    __syncthreads();

    const short* zr = &zh[(wv * 16 + ln) * 136 + q4 * 8];
    const half8 bh0 = *(const half8*)&zr[0];
    const half8 bl0 = *(const half8*)&zr[32];
    const half8 bh1 = *(const half8*)&zr[64];
    const half8 bl1 = *(const half8*)&zr[96];
    const float As  = szf_s[wv * 16 + ln];

    float bs = 3.0e38f;
    int   bi = 1 << 30;

#pragma unroll 4
    for (int ct = 0; ct < 32; ++ct) {
        const short* ap = cbs + ((size_t)(ct * 16 + ln)) * 32 + q4 * 8;
        const half8 ah0 = *(const half8*)&ap[0];
        const half8 al0 = *(const half8*)&ap[512 * 32];
        const half8 ah1 = *(const half8*)&ap[2 * 512 * 32];
        const half8 al1 = *(const half8*)&ap[3 * 512 * 32];
        f32x4 a0 = {0.f, 0.f, 0.f, 0.f};
        f32x4 a1 = {0.f, 0.f, 0.f, 0.f};
        a0 = __builtin_amdgcn_mfma_f32_16x16x32_f16(ah0, bh0, a0, 0, 0, 0);
        a1 = __builtin_amdgcn_mfma_f32_16x16x32_f16(ah0, bl0, a1, 0, 0, 0);
        a1 = __builtin_amdgcn_mfma_f32_16x16x32_f16(al0, bh0, a1, 0, 0, 0);
        a0 = __builtin_amdgcn_mfma_f32_16x16x32_f16(ah1, bh1, a0, 0, 0, 0);
        a1 = __builtin_amdgcn_mfma_f32_16x16x32_f16(ah1, bl1, a1, 0, 0, 0);
        a1 = __builtin_amdgcn_mfma_f32_16x16x32_f16(al1, bh1, a1, 0, 0, 0);
#pragma unroll
        for (int r = 0; r < 4; ++r) {
            const int code = ct * 16 + q4 * 4 + r;
            const float m32 = fmaf(a1[r], 0.000244140625f, a0[r]);
            const float A   = As + c2s[code];
            const float s   = A - 2.0f * m32;
            if (s < bs || (s == bs && code < bi)) { bs = s; bi = code; }
        }
    }
#pragma unroll
    for (int off = 16; off <= 32; off <<= 1) {
        const float os = __shfl_xor(bs, off);
        const int   oi = __shfl_xor(bi, off);
        if (os < bs || (os == bs && oi < bi)) { bs = os; bi = oi; }
    }
    if (q4 == 0) {
        const int t = wv * 16 + ln;
        idxs[t] = bi;
        idx_out[(size_t)n * T_LEN + t0 + t] = (float)bi;
    }
    __syncthreads();

    {
        const int g = tid >> 6, t = tid & 63;
        const int bi2 = idxs[t];
        double ls = 0.0;
        for (int dd = 0; dd < 16; ++dd) {
            const int d = g * 16 + dd;
            const float qv = cb[(size_t)bi2 * 64 + d];
            const float zv = zs[t * 68 + d];
            const double df = (double)qv - (double)zv;
            ls += df * df;
            q[((size_t)(n * 64 + d)) * T_LEN + t0 + t] = qv;
        }
        dred[tid] = ls;
    }
    __syncthreads();
    for (int s = 128; s > 0; s >>= 1) {
        if (tid < s) dred[tid] += dred[tid + s];
        __syncthreads();
    }
    if (tid == 0) atomicAdd(loss, dred[0]);
}

__global__ void fin_k(const double* __restrict__ loss, float* __restrict__ out) {
    if (threadIdx.x == 0 && blockIdx.x == 0)
        out[0] = (float)(1.25 * (*loss) / 4194304.0);
}

extern "C" void kernel_launch(void* const* d_in, const int* in_sizes, int n_in,
                              void* d_out, int out_size, void* d_ws, size_t ws_size,
                              hipStream_t stream) {
    const float* x      = (const float*)d_in[0];
    const float* enc_w1 = (const float*)d_in[1];
    const float* enc_b1 = (const float*)d_in[2];
    const float* bn1_g  = (const float*)d_in[3];
    const float* bn1_b  = (const float*)d_in[4];
    const float* enc_w2 = (const float*)d_in[5];
    const float* enc_b2 = (const float*)d_in[6];
    const float* bn2_g  = (const float*)d_in[7];
    const float* bn2_b  = (const float*)d_in[8];
    const float* enc_w3 = (const float*)d_in[9];
    const float* enc_b3 = (const float*)d_in[10];
    const float* cb     = (const float*)d_in[11];
    const float* dec_w1 = (const float*)d_in[12];
    const float* dec_b1 = (const float*)d_in[13];
    const float* dbn1_g = (const float*)d_in[14];
    const float* dbn1_b = (const float*)d_in[15];
    const float* dec_w2 = (const float*)d_in[16];
    const float* dec_b2 = (const float*)d_in[17];
    const float* dbn2_g = (const float*)d_in[18];
    const float* dbn2_b = (const float*)d_in[19];
    const float* dec_w3 = (const float*)d_in[20];
    const float* dec_b3 = (const float*)d_in[21];

    float* wsf   = (float*)d_ws;
    float* outf  = (float*)d_out;
    float* A     = wsf + OFF_A;
    float* Bb    = wsf + OFF_B;
    float* Z     = wsf + OFF_Z;
    float2* st   = (float2*)(wsf + OFF_ST);
    double* lossp = (double*)(wsf + OFF_LOSS);

    const short* wsE1 = (const short*)(wsf + OFF_WS + WS_E1);
    const short* wsE2 = (const short*)(wsf + OFF_WS + WS_E2);
    const short* wsE3 = (const short*)(wsf + OFF_WS + WS_E3);
    const short* wsD1 = (const short*)(wsf + OFF_WS + WS_D1);
    const short* wsD2 = (const short*)(wsf + OFF_WS + WS_D2);
    const short* wsD3 = (const short*)(wsf + OFF_WS + WS_D3);
    const short* cbs  = (const short*)(wsf + OFF_CBS);

    // partial-stat buffers live in whichever big buffer is dead at that stage
    float2* pE1 = (float2*)Bb;   // enc1: Bb free until enc2 writes it
    float2* pE2 = (float2*)Z;    // enc2: Z free until enc3 writes it
    float2* pD1 = (float2*)A;    // dec1: A free until dec2 writes it
    float2* pD2 = (float2*)Z;    // dec2: Z dead after dec1 consumed it

    prep_k<<<723, 256, 0, stream>>>(enc_w1, enc_w2, enc_w3, cb, wsf);

    // encoder (exact r3 grids)
    fconv_k<80, 128, 3, false, true><<<dim3(512, 2), 256, 0, stream>>>(
        x, wsE1, enc_b1, nullptr, A, pE1);
    stats_k<<<128, 256, 0, stream>>>(pE1, bn1_g, bn1_b, st);
    fconv_k<128, 256, 3, true, true><<<dim3(512, 4), 256, 0, stream>>>(
        A, wsE2, enc_b2, st, Bb, pE2);
    stats_k<<<256, 256, 0, stream>>>(pE2, bn2_g, bn2_b, st);
    fconv_k<256, 64, 1, true, false><<<dim3(1024, 1), 256, 0, stream>>>(
        Bb, wsE3, enc_b3, st, Z, nullptr);

    // decoder splits overwrite (now-dead) encoder splits
    prep2_k<<<696, 256, 0, stream>>>(dec_w1, dec_w2, dec_w3, wsf);

    // vector quantizer
    vq_k<<<1024, 256, 0, stream>>>(Z, cb, cbs, wsf + OFF_C2, Z,
                                   outf + 5242881, lossp);
    fin_k<<<1, 64, 0, stream>>>(lossp, outf + 5242880);

    // decoder
    fconv_k<64, 256, 3, false, true><<<dim3(512, 4), 256, 0, stream>>>(
        Z, wsD1, dec_b1, nullptr, Bb, pD1);
    stats_k<<<256, 256, 0, stream>>>(pD1, dbn1_g, dbn1_b, st);
    fconv_k<256, 128, 3, true, true><<<dim3(512, 2), 256, 0, stream>>>(
        Bb, wsD2, dec_b2, st, A, pD2);
    stats_k<<<128, 256, 0, stream>>>(pD2, dbn2_g, dbn2_b, st);
    fconv_k<128, 80, 3, true, false><<<dim3(512, 2), 256, 0, stream>>>(
        A, wsD3, dec_b3, st, outf, nullptr);
}

// Round 8
// 364.857 us; speedup vs baseline: 1.5167x; 1.0423x over previous
//
#include <hip/hip_runtime.h>
#include <math.h>

#define N_B 16
#define T_LEN 4096

typedef float f32x4  __attribute__((ext_vector_type(4)));
typedef _Float16 half8 __attribute__((ext_vector_type(8)));

// ---- workspace layout (float offsets) ----
static const size_t OFF_A    = 0;            // 16*128*4096
static const size_t OFF_B    = 8388608;      // 16*256*4096
static const size_t OFF_Z    = 25165824;     // 16*64*4096
static const size_t OFF_WS   = 29360128;     // split-weight region
static const size_t OFF_CBS  = 29540352;     // codebook split (32768 floats)
static const size_t OFF_C2   = 29683712;
static const size_t OFF_ST   = 29684736;
static const size_t OFF_LOSS = 29685760;

// split-weight offsets (floats from OFF_WS); decoder reuses after enc convs
static const size_t WS_E1 = 0;        // 3*3*128*32 = 36864 floats
static const size_t WS_E2 = 36864;    // 4*3*256*32 = 98304 floats
static const size_t WS_E3 = 135168;   // 8*1*64*32  = 16384 floats -> 151552
static const size_t WS_D1 = 0;        // 2*3*256*32 = 49152 floats
static const size_t WS_D2 = 49152;    // 8*3*128*32 = 98304 floats
static const size_t WS_D3 = 147456;   // 4*3*80*32  = 30720 floats -> 178176

// scaled f16 split: v = hi + lo * 2^-12, error ~2^-24 relative (f32-grade).
__device__ inline void f2h2(float v, short& hi, short& lo) {
    _Float16 h = (_Float16)v;
    float r = (v - (float)h) * 4096.0f;
    _Float16 l = (_Float16)r;
    hi = __builtin_bit_cast(short, h);
    lo = __builtin_bit_cast(short, l);
}
__device__ inline float h2f(short s) {
    return (float)__builtin_bit_cast(_Float16, s);
}

// fill split-weight fragments: dst layout [(c*KS+k)*2+p][co][32 ci-shorts]
template<int C_IN, int C_OUT, int KS>
__device__ inline void wsplit_fill(const float* __restrict__ w,
                                   short* __restrict__ dst, int e) {
    int i  = e & 31;
    int r  = e >> 5;
    int co = r % C_OUT;
    int r2 = r / C_OUT;          // c*KS + k
    int k  = r2 % KS;
    int c  = r2 / KS;
    int ci = c * 32 + i;
    float v = (ci < C_IN) ? w[((size_t)co * C_IN + ci) * KS + k] : 0.f;
    short h, l; f2h2(v, h, l);
    size_t base = ((size_t)(c * KS + k) * 2 * C_OUT + co) * 32 + i;
    dst[base] = h;
    dst[base + (size_t)C_OUT * 32] = l;
}

__global__ __launch_bounds__(256) void prep_k(
        const float* __restrict__ w1, const float* __restrict__ w2,
        const float* __restrict__ w3, const float* __restrict__ cb,
        float* wsf) {
    int e = blockIdx.x * 256 + threadIdx.x;
    if (e < 36864)        wsplit_fill<80, 128, 3>(w1, (short*)(wsf + OFF_WS + WS_E1), e);
    else if (e < 135168)  wsplit_fill<128, 256, 3>(w2, (short*)(wsf + OFF_WS + WS_E2), e - 36864);
    else if (e < 151552)  wsplit_fill<256, 64, 1>(w3, (short*)(wsf + OFF_WS + WS_E3), e - 135168);
    else if (e < 152064) {
        int c = e - 151552;
        const float* p = cb + (size_t)c * 64;
        double s = 0.0;
        for (int d = 0; d < 64; ++d) { double v = p[d]; s += v * v; }
        wsf[OFF_C2 + c] = (float)s;
    } else if (e < 184832) {
        // codebook split fragments (vq_k): [ks][plane][code][32 d-shorts]
        int e2   = e - 152064;
        int i    = e2 & 31;
        int r    = e2 >> 5;
        int code = r & 511;
        int ks   = r >> 9;
        float v  = cb[(size_t)code * 64 + ks * 32 + i];
        short h, l; f2h2(v, h, l);
        short* dst = (short*)(wsf + OFF_CBS);
        dst[((size_t)(ks * 2 + 0) * 512 + code) * 32 + i] = h;
        dst[((size_t)(ks * 2 + 1) * 512 + code) * 32 + i] = l;
    } else if (e == 184832) {
        *(double*)(wsf + OFF_LOSS) = 0.0;
    }
}

__global__ __launch_bounds__(256) void prep2_k(
        const float* __restrict__ wd1, const float* __restrict__ wd2,
        const float* __restrict__ wd3, float* wsf) {
    int e = blockIdx.x * 256 + threadIdx.x;
    if (e < 49152)        wsplit_fill<64, 256, 3>(wd1, (short*)(wsf + OFF_WS + WS_D1), e);
    else if (e < 147456)  wsplit_fill<256, 128, 3>(wd2, (short*)(wsf + OFF_WS + WS_D2), e - 49152);
    else if (e < 178176)  wsplit_fill<128, 80, 3>(wd3, (short*)(wsf + OFF_WS + WS_D3), e - 147456);
}

// ---- conv1d via scaled-f16 split MFMA (r3/r7 inner loop, 8-wave blocks) ----
// GEMM M=co, N=t, K=ci per k-tap. Block: 512 thr = 8 waves.
// KS=3: CO_TILE=128 (8 co-strips x full TT=128) — staging per MFMA halves vs r7.
// KS=1: CO_TILE=64  (4 co-strips x 2 t-halves, TT=64).
// Maps (HW-verified r1-r7): A[m=lane&15][k=q*8+j], B[k=q*8+j][n=lane&15],
// D[m=q*4+r][n=lane&15].  acc0 += ah*bh ; acc1 += ah*bl + al*bh.
// Per-output MFMA accumulation order identical to r7 -> bitwise-same conv out.
template<int C_IN, int C_OUT, int KS, bool BN_IN, bool STATS>
__global__ __launch_bounds__(512, 4) void fconv_k(
        const float* __restrict__ x, const short* __restrict__ wsp,
        const float* __restrict__ bias, const float2* __restrict__ stats,
        float* __restrict__ out, float2* __restrict__ part) {
    constexpr int NCH  = (C_IN + 31) / 32;
    constexpr int HALO = KS / 2;
    constexpr int TT   = (KS == 1) ? 64 : 128;   // t-tile
    constexpr int WT   = (KS == 1) ? 2 : 1;      // waves along t
    constexpr int WCO  = 8 / WT;                 // waves along co
    constexpr int HT   = TT / WT;                // t per wave
    constexpr int NTT  = HT / 16;                // MFMA t-subtiles per wave
    constexpr int NTILE = T_LEN / TT;
    constexpr int XR   = TT + KS - 1;
    constexpr int RS   = 72;                     // shorts/row (144B, 16B-aligned)
    constexpr int LO   = 40;                     // lo-plane offset within row
    constexpr int TQ   = TT / 4;                 // t-stride for 4-way load

    __shared__ __align__(16) short xs[XR * RS];

    const int tid  = threadIdx.x;
    const int lane = tid & 63;
    const int wv   = tid >> 6;
    const int wvc  = wv % WCO;                   // co strip
    const int wvt  = wv / WCO;                   // t half (KS==1 only)
    const int ln   = lane & 15;
    const int q    = lane >> 4;

    const int n    = blockIdx.x / NTILE;
    const int t0   = (blockIdx.x % NTILE) * TT;
    const int co0  = blockIdx.y * (WCO * 16);
    const int co_l = co0 + wvc * 16 + ln;        // A-fragment row for this lane

    f32x4 a0[NTT], a1[NTT];
#pragma unroll
    for (int tt = 0; tt < NTT; ++tt)
#pragma unroll
        for (int i = 0; i < 4; ++i) { a0[tt][i] = 0.f; a1[tt][i] = 0.f; }

#pragma unroll 1
    for (int c = 0; c < NCH; ++c) {
        // ---- w fragments: direct global loads (L2-hot, coalesced 16B) ----
        half8 ah[KS], al[KS];
        {
            half8 z = {0, 0, 0, 0, 0, 0, 0, 0};
#pragma unroll
            for (int k = 0; k < KS; ++k) {
                const short* wp = wsp
                    + ((size_t)(c * KS + k) * 2 * C_OUT + co_l) * 32 + q * 8;
                ah[k] = (co_l < C_OUT) ? *(const half8*)wp : z;
                al[k] = (co_l < C_OUT) ? *(const half8*)(wp + (size_t)C_OUT * 32) : z;
            }
        }

        __syncthreads();
        // ---- stage x tile [t-row][ci] with split planes ----
        for (int e = tid; e < 32 * TQ; e += 512) {
            const int ci  = e / TQ;
            const int tq  = e % TQ;
            const int cig = c * 32 + ci;
            float v[4] = {0.f, 0.f, 0.f, 0.f};
            if (cig < C_IN) {
                const float* xp = x + ((size_t)(n * C_IN + cig)) * T_LEN + t0 + tq;
#pragma unroll
                for (int j = 0; j < 4; ++j) v[j] = xp[TQ * j];
                if (BN_IN) {
                    float2 s = stats[cig];
#pragma unroll
                    for (int j = 0; j < 4; ++j) v[j] = fmaxf(fmaf(v[j], s.x, s.y), 0.f);
                }
            }
#pragma unroll
            for (int j = 0; j < 4; ++j) {
                short h, l; f2h2(v[j], h, l);
                short* p = &xs[(HALO + tq + TQ * j) * RS + ci];
                p[0]  = h;
                p[LO] = l;
            }
        }
        if (KS == 3) {
            if (tid < 64) {
                const int ci   = tid & 31;
                const int side = tid >> 5;
                const int cig  = c * 32 + ci;
                const int gt   = side ? (t0 + TT) : (t0 - 1);
                float v = 0.f;
                if (cig < C_IN && gt >= 0 && gt < T_LEN) {
                    v = x[((size_t)(n * C_IN + cig)) * T_LEN + gt];
                    if (BN_IN) {
                        float2 s = stats[cig];
                        v = fmaxf(fmaf(v, s.x, s.y), 0.f);
                    }
                }
                short h, l; f2h2(v, h, l);
                short* p = &xs[(side ? (XR - 1) : 0) * RS + ci];
                p[0] = h; p[LO] = l;
            }
        }
        __syncthreads();

        // ---- MFMA: 3-product split (b128 LDS reads, r3/r7-proven) ----
#pragma unroll
        for (int k = 0; k < KS; ++k) {
#pragma unroll
            for (int tt = 0; tt < NTT; ++tt) {
                const short* xr = &xs[(wvt * HT + tt * 16 + ln + k) * RS + q * 8];
                half8 bh = *(const half8*)&xr[0];
                half8 bl = *(const half8*)&xr[LO];
                a0[tt] = __builtin_amdgcn_mfma_f32_16x16x32_f16(ah[k], bh, a0[tt], 0, 0, 0);
                a1[tt] = __builtin_amdgcn_mfma_f32_16x16x32_f16(ah[k], bl, a1[tt], 0, 0, 0);
                a1[tt] = __builtin_amdgcn_mfma_f32_16x16x32_f16(al[k], bh, a1[tt], 0, 0, 0);
            }
        }
    }

    // epilogue: lane reg r -> D[co = co0+wvc*16+q*4+r][t = t0+wvt*HT+tt*16+ln]
    // + optional fused BN partial sums (f32, 16-lane shfl reduce over ln).
    // STATS only used with KS==3 (WT==1), so plinear needs no wvt term.
    const int plinear = blockIdx.y * (N_B * NTILE) + blockIdx.x;
#pragma unroll
    for (int r = 0; r < 4; ++r) {
        const int co = co0 + wvc * 16 + q * 4 + r;
        float s1 = 0.f, s2 = 0.f;
        if (co < C_OUT) {
            const float bv = bias[co];
            float* op = out + ((size_t)(n * C_OUT + co)) * T_LEN + t0 + wvt * HT + ln;
#pragma unroll
            for (int tt = 0; tt < NTT; ++tt) {
                const float v = fmaf(a1[tt][r], 0.000244140625f, a0[tt][r]) + bv;
                op[tt * 16] = v;
                if (STATS) { s1 += v; s2 = fmaf(v, v, s2); }
            }
        }
        if (STATS) {
#pragma unroll
            for (int off = 1; off <= 8; off <<= 1) {
                s1 += __shfl_xor(s1, off);
                s2 += __shfl_xor(s2, off);
            }
            if (ln == 0)
                part[(size_t)plinear * 128 + wvc * 16 + q * 4 + r] =
                    make_float2(s1, s2);
        }
    }
}

// ---- BN stats: reduce 512 per-block float2 partials per channel (f64) ----
// part layout: [coblk*512 + block][128 co-within-tile]
__global__ __launch_bounds__(256) void stats_k(
        const float2* __restrict__ part, const float* __restrict__ g,
        const float* __restrict__ b, float2* __restrict__ stats) {
    const int c = blockIdx.x;
    const int tid = threadIdx.x;
    double s1 = 0.0, s2 = 0.0;
    for (int j = tid; j < 512; j += 256) {
        float2 v = part[((size_t)(c >> 7) * 512 + j) * 128 + (c & 127)];
        s1 += (double)v.x; s2 += (double)v.y;
    }
    __shared__ double r1[256], r2[256];
    r1[tid] = s1; r2[tid] = s2;
    __syncthreads();
    for (int s = 128; s > 0; s >>= 1) {
        if (tid < s) { r1[tid] += r1[tid + s]; r2[tid] += r2[tid + s]; }
        __syncthreads();
    }
    if (tid == 0) {
        double m   = r1[0] / 65536.0;
        double var = r2[0] / 65536.0 - m * m;
        double sc  = (double)g[c] / sqrt(var + 1e-5);
        stats[c] = make_float2((float)sc, (float)((double)b[c] - m * sc));
    }
}

// ---- VQ via scaled-f16 split MFMA (16x16x32, r3-proven, verbatim) ----
__global__ __launch_bounds__(256) void vq_k(
        const float* __restrict__ z, const float* __restrict__ cb,
        const short* __restrict__ cbs, const float* __restrict__ c2,
        float* __restrict__ q, float* __restrict__ idx_out,
        double* __restrict__ loss) {
    __shared__ __align__(16) float zs[64 * 68];
    __shared__ __align__(16) short zh[64 * 136];
    __shared__ float  c2s[512];
    __shared__ float  szf_s[64];
    __shared__ int    idxs[64];
    __shared__ double dred[256];

    const int tid  = threadIdx.x;
    const int lane = tid & 63;
    const int wv   = tid >> 6;
    const int ln   = lane & 15;
    const int q4   = lane >> 4;
    const int n    = blockIdx.x >> 6;
    const int t0   = (blockIdx.x & 63) * 64;

    for (int e = tid; e < 512; e += 256) c2s[e] = c2[e];
    for (int e = tid; e < 1024; e += 256) {
        const int d  = e >> 4;
        const int tq = e & 15;
        const float* zp = z + ((size_t)(n * 64 + d)) * T_LEN + t0 + tq;
        const int ks = d >> 5, i = d & 31;
#pragma unroll
        for (int j = 0; j < 4; ++j) {
            const int t = tq + 16 * j;
            float v = zp[16 * j];
            zs[t * 68 + d] = v;
            short h, l; f2h2(v, h, l);
            zh[t * 136 + (ks * 2 + 0) * 32 + i] = h;
            zh[t * 136 + (ks * 2 + 1) * 32 + i] = l;
        }
    }
    __syncthreads();
    if (tid < 64) {
        double s = 0.0;
        const float* zr = &zs[tid * 68];
        for (int d = 0; d < 64; ++d) { double v = zr[d]; s += v * v; }
        szf_s[tid] = (float)s;
    }
    __syncthreads();

    const short* zr = &zh[(wv * 16 + ln) * 136 + q4 * 8];
    const half8 bh0 = *(const half8*)&zr[0];
    const half8 bl0 = *(const half8*)&zr[32];
    const half8 bh1 = *(const half8*)&zr[64];
    const half8 bl1 = *(const half8*)&zr[96];
    const float As  = szf_s[wv * 16 + ln];

    float bs = 3.0e38f;
    int   bi = 1 << 30;

#pragma unroll 4
    for (int ct = 0; ct < 32; ++ct) {
        const short* ap = cbs + ((size_t)(ct * 16 + ln)) * 32 + q4 * 8;
        const half8 ah0 = *(const half8*)&ap[0];
        const half8 al0 = *(const half8*)&ap[512 * 32];
        const half8 ah1 = *(const half8*)&ap[2 * 512 * 32];
        const half8 al1 = *(const half8*)&ap[3 * 512 * 32];
        f32x4 a0 = {0.f, 0.f, 0.f, 0.f};
        f32x4 a1 = {0.f, 0.f, 0.f, 0.f};
        a0 = __builtin_amdgcn_mfma_f32_16x16x32_f16(ah0, bh0, a0, 0, 0, 0);
        a1 = __builtin_amdgcn_mfma_f32_16x16x32_f16(ah0, bl0, a1, 0, 0, 0);
        a1 = __builtin_amdgcn_mfma_f32_16x16x32_f16(al0, bh0, a1, 0, 0, 0);
        a0 = __builtin_amdgcn_mfma_f32_16x16x32_f16(ah1, bh1, a0, 0, 0, 0);
        a1 = __builtin_amdgcn_mfma_f32_16x16x32_f16(ah1, bl1, a1, 0, 0, 0);
        a1 = __builtin_amdgcn_mfma_f32_16x16x32_f16(al1, bh1, a1, 0, 0, 0);
#pragma unroll
        for (int r = 0; r < 4; ++r) {
            const int code = ct * 16 + q4 * 4 + r;
            const float m32 = fmaf(a1[r], 0.000244140625f, a0[r]);
            const float A   = As + c2s[code];
            const float s   = A - 2.0f * m32;
            if (s < bs || (s == bs && code < bi)) { bs = s; bi = code; }
        }
    }
#pragma unroll
    for (int off = 16; off <= 32; off <<= 1) {
        const float os = __shfl_xor(bs, off);
        const int   oi = __shfl_xor(bi, off);
        if (os < bs || (os == bs && oi < bi)) { bs = os; bi = oi; }
    }
    if (q4 == 0) {
        const int t = wv * 16 + ln;
        idxs[t] = bi;
        idx_out[(size_t)n * T_LEN + t0 + t] = (float)bi;
    }
    __syncthreads();

    {
        const int g = tid >> 6, t = tid & 63;
        const int bi2 = idxs[t];
        double ls = 0.0;
        for (int dd = 0; dd < 16; ++dd) {
            const int d = g * 16 + dd;
            const float qv = cb[(size_t)bi2 * 64 + d];
            const float zv = zs[t * 68 + d];
            const double df = (double)qv - (double)zv;
            ls += df * df;
            q[((size_t)(n * 64 + d)) * T_LEN + t0 + t] = qv;
        }
        dred[tid] = ls;
    }
    __syncthreads();
    for (int s = 128; s > 0; s >>= 1) {
        if (tid < s) dred[tid] += dred[tid + s];
        __syncthreads();
    }
    if (tid == 0) atomicAdd(loss, dred[0]);
}

__global__ void fin_k(const double* __restrict__ loss, float* __restrict__ out) {
    if (threadIdx.x == 0 && blockIdx.x == 0)
        out[0] = (float)(1.25 * (*loss) / 4194304.0);
}

extern "C" void kernel_launch(void* const* d_in, const int* in_sizes, int n_in,
                              void* d_out, int out_size, void* d_ws, size_t ws_size,
                              hipStream_t stream) {
    const float* x      = (const float*)d_in[0];
    const float* enc_w1 = (const float*)d_in[1];
    const float* enc_b1 = (const float*)d_in[2];
    const float* bn1_g  = (const float*)d_in[3];
    const float* bn1_b  = (const float*)d_in[4];
    const float* enc_w2 = (const float*)d_in[5];
    const float* enc_b2 = (const float*)d_in[6];
    const float* bn2_g  = (const float*)d_in[7];
    const float* bn2_b  = (const float*)d_in[8];
    const float* enc_w3 = (const float*)d_in[9];
    const float* enc_b3 = (const float*)d_in[10];
    const float* cb     = (const float*)d_in[11];
    const float* dec_w1 = (const float*)d_in[12];
    const float* dec_b1 = (const float*)d_in[13];
    const float* dbn1_g = (const float*)d_in[14];
    const float* dbn1_b = (const float*)d_in[15];
    const float* dec_w2 = (const float*)d_in[16];
    const float* dec_b2 = (const float*)d_in[17];
    const float* dbn2_g = (const float*)d_in[18];
    const float* dbn2_b = (const float*)d_in[19];
    const float* dec_w3 = (const float*)d_in[20];
    const float* dec_b3 = (const float*)d_in[21];

    float* wsf   = (float*)d_ws;
    float* outf  = (float*)d_out;
    float* A     = wsf + OFF_A;
    float* Bb    = wsf + OFF_B;
    float* Z     = wsf + OFF_Z;
    float2* st   = (float2*)(wsf + OFF_ST);
    double* lossp = (double*)(wsf + OFF_LOSS);

    const short* wsE1 = (const short*)(wsf + OFF_WS + WS_E1);
    const short* wsE2 = (const short*)(wsf + OFF_WS + WS_E2);
    const short* wsE3 = (const short*)(wsf + OFF_WS + WS_E3);
    const short* wsD1 = (const short*)(wsf + OFF_WS + WS_D1);
    const short* wsD2 = (const short*)(wsf + OFF_WS + WS_D2);
    const short* wsD3 = (const short*)(wsf + OFF_WS + WS_D3);
    const short* cbs  = (const short*)(wsf + OFF_CBS);

    // partial-stat buffers live in whichever big buffer is dead at that stage
    float2* pE1 = (float2*)Bb;   // enc1: Bb free until enc2 writes it
    float2* pE2 = (float2*)Z;    // enc2: Z free until enc3 writes it
    float2* pD1 = (float2*)A;    // dec1: A free until dec2 writes it
    float2* pD2 = (float2*)Z;    // dec2: Z dead after dec1 consumed it

    prep_k<<<723, 256, 0, stream>>>(enc_w1, enc_w2, enc_w3, cb, wsf);

    // encoder — 8-wave blocks, CO_TILE=128 (KS=3) / 64x2t (KS=1)
    fconv_k<80, 128, 3, false, true><<<dim3(512, 1), 512, 0, stream>>>(
        x, wsE1, enc_b1, nullptr, A, pE1);
    stats_k<<<128, 256, 0, stream>>>(pE1, bn1_g, bn1_b, st);
    fconv_k<128, 256, 3, true, true><<<dim3(512, 2), 512, 0, stream>>>(
        A, wsE2, enc_b2, st, Bb, pE2);
    stats_k<<<256, 256, 0, stream>>>(pE2, bn2_g, bn2_b, st);
    fconv_k<256, 64, 1, true, false><<<dim3(1024, 1), 512, 0, stream>>>(
        Bb, wsE3, enc_b3, st, Z, nullptr);

    // decoder splits overwrite (now-dead) encoder splits
    prep2_k<<<696, 256, 0, stream>>>(dec_w1, dec_w2, dec_w3, wsf);

    // vector quantizer
    vq_k<<<1024, 256, 0, stream>>>(Z, cb, cbs, wsf + OFF_C2, Z,
                                   outf + 5242881, lossp);
    fin_k<<<1, 64, 0, stream>>>(lossp, outf + 5242880);

    // decoder
    fconv_k<64, 256, 3, false, true><<<dim3(512, 2), 512, 0, stream>>>(
        Z, wsD1, dec_b1, nullptr, Bb, pD1);
    stats_k<<<256, 256, 0, stream>>>(pD1, dbn1_g, dbn1_b, st);
    fconv_k<256, 128, 3, true, true><<<dim3(512, 1), 512, 0, stream>>>(
        Bb, wsD2, dec_b2, st, A, pD2);
    stats_k<<<128, 256, 0, stream>>>(pD2, dbn2_g, dbn2_b, st);
    fconv_k<128, 80, 3, true, false><<<dim3(512, 1), 512, 0, stream>>>(
        A, wsD3, dec_b3, st, outf, nullptr);
}